// Round 2
// baseline (475.472 us; speedup 1.0000x reference)
//
#include <hip/hip_runtime.h>

// ---------------- problem constants ----------------
#define NCONS 10000
#define NCOLSN 10000
#define NNODES 20000         // NCONS + NCOLSN
#define NEDGE 200000
#define NETOT 220000         // NEDGE + NNODES self loops
#define NEG_SLOPE 0.2f

typedef unsigned short u16;
typedef __attribute__((ext_vector_type(8))) short bf16x8;
typedef __attribute__((ext_vector_type(4))) float f32x4;

__device__ __forceinline__ float bf2f(u16 u) {
  return __uint_as_float(((unsigned int)u) << 16);
}
__device__ __forceinline__ u16 f2bf(float f) {
  unsigned int x = __float_as_uint(f);
  return (u16)((x + 0x7fffu + ((x >> 16) & 1u)) >> 16);
}
__device__ __forceinline__ float lrelu(float v) {
  return v >= 0.f ? v : NEG_SLOPE * v;
}

// ---------------- f32 -> bf16 convert ----------------
__global__ void cvt_bf16(const float* __restrict__ in, u16* __restrict__ out, int n) {
  int i = blockIdx.x * 256 + threadIdx.x;
  if (i < n) out[i] = f2bf(in[i]);
}

// ---------------- CSR build ----------------
__global__ void zero_i32(int* p, int n) {
  int i = blockIdx.x * 256 + threadIdx.x;
  if (i < n) p[i] = 0;
}

__global__ void count_edges(const int* __restrict__ edges, int* __restrict__ counts) {
  int i = blockIdx.x * 256 + threadIdx.x;
  if (i >= NETOT) return;
  int dst = (i < NEDGE) ? edges[NEDGE + i] : (i - NEDGE);
  atomicAdd(&counts[dst], 1);
}

// single-block scan: offsets[0..N], cursor[i] = offsets[i]
__global__ void scan_counts(const int* __restrict__ counts, int* __restrict__ offsets,
                            int* __restrict__ cursor) {
  __shared__ int sh[256];
  __shared__ int carry;
  int t = threadIdx.x;
  if (t == 0) { carry = 0; offsets[0] = 0; }
  __syncthreads();
  for (int base = 0; base < NNODES; base += 256) {
    int i = base + t;
    int v = (i < NNODES) ? counts[i] : 0;
    sh[t] = v;
    __syncthreads();
    for (int d = 1; d < 256; d <<= 1) {
      int add = (t >= d) ? sh[t - d] : 0;
      __syncthreads();
      sh[t] += add;
      __syncthreads();
    }
    int inc = sh[t] + carry;   // inclusive prefix incl. carry
    if (i < NNODES) { offsets[i + 1] = inc; cursor[i] = inc - v; }
    __syncthreads();
    if (t == 255) carry = inc;
    __syncthreads();
  }
}

__global__ void fill_edges(const int* __restrict__ edges, int* __restrict__ cursor,
                           int* __restrict__ csr_src) {
  int i = blockIdx.x * 256 + threadIdx.x;
  if (i >= NETOT) return;
  int src, dst;
  if (i < NEDGE) { src = edges[i]; dst = edges[NEDGE + i]; }
  else { src = dst = i - NEDGE; }
  int pos = atomicAdd(&cursor[dst], 1);
  csr_src[pos] = src;
}

// ---------------- layer 0: node/col embed (tile(x,(1,2)) folded), f32 in -> bf16 out ----------------
__global__ void embed0(const float* __restrict__ cons, const float* __restrict__ cols,
                       const float* __restrict__ nW, const float* __restrict__ nb,
                       const float* __restrict__ cW, const float* __restrict__ cb,
                       u16* __restrict__ emb) {
  int idx = blockIdx.x * 256 + threadIdx.x;
  if (idx >= NNODES * 128) return;
  int row = idx >> 7, o = idx & 127;
  float acc;
  if (row < NCONS) {
    acc = nb[o];
    #pragma unroll
    for (int k = 0; k < 4; ++k)
      acc += cons[row * 4 + k] * (nW[o * 8 + k] + nW[o * 8 + 4 + k]);
  } else {
    int r = row - NCONS;
    acc = cb[o];
    #pragma unroll
    for (int k = 0; k < 8; ++k)
      acc += cols[r * 8 + k] * (cW[o * 16 + k] + cW[o * 16 + 8 + k]);
  }
  emb[idx] = f2bf(fmaxf(acc, 0.f));
}

// ---------------- GEMM: C[M,N] = A[M,K] @ B[N,K]^T (+bias), bf16 in, bf16/f32 out ----------------
// block 256 = 4 waves; block tile 64(M)x64(N); each wave: 16(M)x64(N)
template <bool BIAS, bool OUTF32>
__global__ __launch_bounds__(256) void gemm_bt(const u16* __restrict__ A, const u16* __restrict__ B,
                                               const float* __restrict__ bias, void* __restrict__ Cv,
                                               int M, int N, int K) {
  int wave = threadIdx.x >> 6;
  int lane = threadIdx.x & 63;
  int quad = lane >> 4;
  int m0 = blockIdx.x * 64 + wave * 16;
  int n0 = blockIdx.y * 64;
  int row = m0 + (lane & 15);
  int rr = row < M ? row : M - 1;   // clamp loads; stores guarded
  f32x4 acc[4] = {f32x4{0,0,0,0}, f32x4{0,0,0,0}, f32x4{0,0,0,0}, f32x4{0,0,0,0}};
  for (int k0 = 0; k0 < K; k0 += 32) {
    bf16x8 a = *(const bf16x8*)(A + (size_t)rr * K + k0 + quad * 8);
    #pragma unroll
    for (int ns = 0; ns < 4; ++ns) {
      int col = n0 + ns * 16 + (lane & 15);
      bf16x8 b = *(const bf16x8*)(B + (size_t)col * K + k0 + quad * 8);
      acc[ns] = __builtin_amdgcn_mfma_f32_16x16x32_bf16(a, b, acc[ns], 0, 0, 0);
    }
  }
  #pragma unroll
  for (int ns = 0; ns < 4; ++ns) {
    int col = n0 + ns * 16 + (lane & 15);
    float bv = BIAS ? bias[col] : 0.f;
    #pragma unroll
    for (int r = 0; r < 4; ++r) {
      int orow = m0 + quad * 4 + r;
      if (orow < M) {
        float v = acc[ns][r] + bv;
        if (OUTF32) ((float*)Cv)[(size_t)orow * N + col] = v;
        else        ((u16*)Cv)[(size_t)orow * N + col] = f2bf(v);
      }
    }
  }
}

// ---------------- attention dot products ----------------
// layer1: xp bf16 [N,8,128] -> a_src/a_dst f32 [N,8]
__global__ void attn_dots1(const u16* __restrict__ xp, const float* __restrict__ att_s,
                           const float* __restrict__ att_d, float* __restrict__ a_src,
                           float* __restrict__ a_dst) {
  int node = blockIdx.x;
  int l = threadIdx.x;   // 64
  const u16* xrow = xp + (size_t)node * 1024;
  for (int h = 0; h < 8; ++h) {
    float x0 = bf2f(xrow[h * 128 + l]);
    float x1 = bf2f(xrow[h * 128 + 64 + l]);
    float s = x0 * att_s[h * 128 + l] + x1 * att_s[h * 128 + 64 + l];
    float d = x0 * att_d[h * 128 + l] + x1 * att_d[h * 128 + 64 + l];
    #pragma unroll
    for (int w = 32; w >= 1; w >>= 1) {
      s += __shfl_xor(s, w, 64);
      d += __shfl_xor(d, w, 64);
    }
    if (l == 0) { a_src[node * 8 + h] = s; a_dst[node * 8 + h] = d; }
  }
}

// layer2: xp bf16 [N,128] -> scalars
__global__ void attn_dots2(const u16* __restrict__ xp, const float* __restrict__ att_s,
                           const float* __restrict__ att_d, float* __restrict__ a_src,
                           float* __restrict__ a_dst) {
  int node = blockIdx.x;
  int l = threadIdx.x;
  const u16* xrow = xp + (size_t)node * 128;
  float x0 = bf2f(xrow[l]);
  float x1 = bf2f(xrow[64 + l]);
  float s = x0 * att_s[l] + x1 * att_s[64 + l];
  float d = x0 * att_d[l] + x1 * att_d[64 + l];
  #pragma unroll
  for (int w = 32; w >= 1; w >>= 1) {
    s += __shfl_xor(s, w, 64);
    d += __shfl_xor(d, w, 64);
  }
  if (l == 0) { a_src[node] = s; a_dst[node] = d; }
}

// ---------------- GAT aggregation layer 1 (H=8, C=128) ----------------
// one block (256 thr) per dst node; thread t: head h=t>>5, lane-in-head l=t&31
__global__ __launch_bounds__(256) void agg1(const int* __restrict__ offs,
                                            const int* __restrict__ csr_src,
                                            const float* __restrict__ a_src,
                                            const float* __restrict__ a_dst,
                                            const u16* __restrict__ xp,
                                            const float* __restrict__ bias,
                                            u16* __restrict__ out) {
  int dst = blockIdx.x;
  int t = threadIdx.x;
  int h = t >> 5, l = t & 31;
  __shared__ float m_sh[8], inv_sh[8], adst_sh[8];
  int off = offs[dst];
  int deg = offs[dst + 1] - off;
  if (t < 8) adst_sh[t] = a_dst[dst * 8 + t];
  __syncthreads();
  float ad = adst_sh[h];
  // phase 1: segment max
  float mx = -1e30f;
  for (int j = l; j < deg; j += 32) {
    int s = csr_src[off + j];
    mx = fmaxf(mx, lrelu(a_src[s * 8 + h] + ad));
  }
  #pragma unroll
  for (int w = 16; w >= 1; w >>= 1) mx = fmaxf(mx, __shfl_xor(mx, w, 32));
  if (l == 0) m_sh[h] = mx;
  __syncthreads();
  mx = m_sh[h];
  // phase 2: denom
  float sum = 0.f;
  for (int j = l; j < deg; j += 32) {
    int s = csr_src[off + j];
    sum += __expf(lrelu(a_src[s * 8 + h] + ad) - mx);
  }
  #pragma unroll
  for (int w = 16; w >= 1; w >>= 1) sum += __shfl_xor(sum, w, 32);
  if (l == 0) inv_sh[h] = 1.f / (sum + 1e-16f);
  __syncthreads();
  float inv = inv_sh[h];
  // phase 3: weighted gather-accumulate; thread owns 4 channels of head h
  int c4 = l * 4;
  float a0 = 0.f, a1 = 0.f, a2 = 0.f, a3 = 0.f;
  for (int j = 0; j < deg; ++j) {
    int s = csr_src[off + j];
    float alpha = __expf(lrelu(a_src[s * 8 + h] + ad) - mx) * inv;
    const u16* prow = xp + (size_t)s * 1024 + h * 128 + c4;
    ushort4 u = *(const ushort4*)prow;
    a0 += alpha * bf2f(u.x);
    a1 += alpha * bf2f(u.y);
    a2 += alpha * bf2f(u.z);
    a3 += alpha * bf2f(u.w);
  }
  int cg = h * 128 + c4;
  size_t obase = (size_t)dst * 1024 + cg;
  out[obase + 0] = f2bf(fmaxf(a0 + bias[cg + 0], 0.f));
  out[obase + 1] = f2bf(fmaxf(a1 + bias[cg + 1], 0.f));
  out[obase + 2] = f2bf(fmaxf(a2 + bias[cg + 2], 0.f));
  out[obase + 3] = f2bf(fmaxf(a3 + bias[cg + 3], 0.f));
}

// ---------------- GAT aggregation layer 2 (H=1, C=128) ----------------
// one wave per dst node
__global__ __launch_bounds__(64) void agg2(const int* __restrict__ offs,
                                           const int* __restrict__ csr_src,
                                           const float* __restrict__ a_src,
                                           const float* __restrict__ a_dst,
                                           const u16* __restrict__ xp,
                                           const float* __restrict__ bias,
                                           u16* __restrict__ out) {
  int dst = blockIdx.x;
  int l = threadIdx.x;
  int off = offs[dst];
  int deg = offs[dst + 1] - off;
  float ad = a_dst[dst];
  float mx = -1e30f;
  for (int j = l; j < deg; j += 64) {
    int s = csr_src[off + j];
    mx = fmaxf(mx, lrelu(a_src[s] + ad));
  }
  #pragma unroll
  for (int w = 32; w >= 1; w >>= 1) mx = fmaxf(mx, __shfl_xor(mx, w, 64));
  float sum = 0.f;
  for (int j = l; j < deg; j += 64) {
    int s = csr_src[off + j];
    sum += __expf(lrelu(a_src[s] + ad) - mx);
  }
  #pragma unroll
  for (int w = 32; w >= 1; w >>= 1) sum += __shfl_xor(sum, w, 64);
  float inv = 1.f / (sum + 1e-16f);
  // each lane owns channels 2l, 2l+1
  float a0 = 0.f, a1 = 0.f;
  for (int j = 0; j < deg; ++j) {
    int s = csr_src[off + j];
    float alpha = __expf(lrelu(a_src[s] + ad) - mx) * inv;
    ushort2 u = *(const ushort2*)(xp + (size_t)s * 128 + l * 2);
    a0 += alpha * bf2f(u.x);
    a1 += alpha * bf2f(u.y);
  }
  int c = l * 2;
  size_t obase = (size_t)dst * 128 + c;
  out[obase + 0] = f2bf(fmaxf(a0 + bias[c + 0], 0.f));
  out[obase + 1] = f2bf(fmaxf(a1 + bias[c + 1], 0.f));
}

// ---------------- launch ----------------
extern "C" void kernel_launch(void* const* d_in, const int* in_sizes, int n_in,
                              void* d_out, int out_size, void* d_ws, size_t ws_size,
                              hipStream_t stream) {
  const float* cons    = (const float*)d_in[0];
  const float* cols    = (const float*)d_in[1];
  const float* node_W  = (const float*)d_in[2];
  const float* node_b  = (const float*)d_in[3];
  const float* col_W   = (const float*)d_in[4];
  const float* col_b   = (const float*)d_in[5];
  const float* W1      = (const float*)d_in[6];
  const float* att_s1  = (const float*)d_in[7];
  const float* att_d1  = (const float*)d_in[8];
  const float* b1      = (const float*)d_in[9];
  const float* W2      = (const float*)d_in[10];
  const float* att_s2  = (const float*)d_in[11];
  const float* att_d2  = (const float*)d_in[12];
  const float* b2      = (const float*)d_in[13];
  const float* out_W   = (const float*)d_in[14];
  const float* out_b   = (const float*)d_in[15];
  const int* edges     = (const int*)d_in[16];

  char* p = (char*)d_ws;
  auto alloc = [&](size_t bytes) {
    char* r = p;
    p += (bytes + 255) & ~(size_t)255;
    return r;
  };
  u16* emb0   = (u16*)alloc((size_t)NNODES * 128 * 2);   // bf16
  u16* xp1    = (u16*)alloc((size_t)NNODES * 1024 * 2);  // bf16
  u16* emb2   = (u16*)alloc((size_t)NNODES * 1024 * 2);  // bf16
  u16* xp2    = (u16*)alloc((size_t)NNODES * 128 * 2);   // bf16
  u16* emb3   = (u16*)alloc((size_t)NNODES * 128 * 2);   // bf16
  u16* W1bf   = (u16*)alloc((size_t)1024 * 128 * 2);
  u16* W2bf   = (u16*)alloc((size_t)128 * 1024 * 2);
  u16* oWbf   = (u16*)alloc((size_t)128 * 128 * 2);
  float* as1  = (float*)alloc((size_t)NNODES * 8 * 4);
  float* ad1  = (float*)alloc((size_t)NNODES * 8 * 4);
  float* as2  = (float*)alloc((size_t)NNODES * 4);
  float* ad2  = (float*)alloc((size_t)NNODES * 4);
  int* counts = (int*)alloc((size_t)NNODES * 4);
  int* offs   = (int*)alloc((size_t)(NNODES + 1) * 4);
  int* cursor = (int*)alloc((size_t)NNODES * 4);
  int* csrsrc = (int*)alloc((size_t)NETOT * 4);

  // CSR build
  zero_i32<<<(NNODES + 255) / 256, 256, 0, stream>>>(counts, NNODES);
  count_edges<<<(NETOT + 255) / 256, 256, 0, stream>>>(edges, counts);
  scan_counts<<<1, 256, 0, stream>>>(counts, offs, cursor);
  fill_edges<<<(NETOT + 255) / 256, 256, 0, stream>>>(edges, cursor, csrsrc);

  // weight conversions f32 -> bf16
  cvt_bf16<<<(1024 * 128 + 255) / 256, 256, 0, stream>>>(W1, W1bf, 1024 * 128);
  cvt_bf16<<<(128 * 1024 + 255) / 256, 256, 0, stream>>>(W2, W2bf, 128 * 1024);
  cvt_bf16<<<(128 * 128 + 255) / 256, 256, 0, stream>>>(out_W, oWbf, 128 * 128);

  // layer 0 embed
  embed0<<<(NNODES * 128 + 255) / 256, 256, 0, stream>>>(cons, cols, node_W, node_b,
                                                         col_W, col_b, emb0);

  // GAT layer 1
  gemm_bt<false, false><<<dim3((NNODES + 63) / 64, 1024 / 64), 256, 0, stream>>>(
      emb0, W1bf, nullptr, xp1, NNODES, 1024, 128);
  attn_dots1<<<NNODES, 64, 0, stream>>>(xp1, att_s1, att_d1, as1, ad1);
  agg1<<<NNODES, 256, 0, stream>>>(offs, csrsrc, as1, ad1, xp1, b1, emb2);

  // GAT layer 2
  gemm_bt<false, false><<<dim3((NNODES + 63) / 64, 128 / 64), 256, 0, stream>>>(
      emb2, W2bf, nullptr, xp2, NNODES, 128, 1024);
  attn_dots2<<<NNODES, 64, 0, stream>>>(xp2, att_s2, att_d2, as2, ad2);
  agg2<<<NNODES, 64, 0, stream>>>(offs, csrsrc, as2, ad2, xp2, b2, emb3);

  // output projection: rows 10000..19999, f32 out with bias
  gemm_bt<true, true><<<dim3((NCOLSN + 63) / 64, 128 / 64), 256, 0, stream>>>(
      emb3 + (size_t)NCONS * 128, oWbf, out_b, d_out, NCOLSN, 128, 128);
}

// Round 3
// 418.726 us; speedup vs baseline: 1.1355x; 1.1355x over previous
//
#include <hip/hip_runtime.h>

// ---------------- problem constants ----------------
#define NCONS 10000
#define NCOLSN 10000
#define NNODES 20000         // NCONS + NCOLSN
#define NEDGE 200000
#define NETOT 220000         // NEDGE + NNODES self loops
#define NEG_SLOPE 0.2f
#define NSCANB 79            // ceil(NNODES/256)

typedef unsigned short u16;
typedef __attribute__((ext_vector_type(8))) short bf16x8;
typedef __attribute__((ext_vector_type(4))) float f32x4;

__device__ __forceinline__ float bf2f(u16 u) {
  return __uint_as_float(((unsigned int)u) << 16);
}
__device__ __forceinline__ u16 f2bf(float f) {
  unsigned int x = __float_as_uint(f);
  return (u16)((x + 0x7fffu + ((x >> 16) & 1u)) >> 16);
}
__device__ __forceinline__ float lrelu(float v) {
  return v >= 0.f ? v : NEG_SLOPE * v;
}

// ---------------- small utils ----------------
__global__ void cvt_bf16(const float* __restrict__ in, u16* __restrict__ out, int n) {
  int i = blockIdx.x * 256 + threadIdx.x;
  if (i < n) out[i] = f2bf(in[i]);
}
__global__ void zero_i32(int* p, int n) {
  int i = blockIdx.x * 256 + threadIdx.x;
  if (i < n) p[i] = 0;
}
__global__ void zero_f32(float* p, int n) {
  int i = blockIdx.x * 256 + threadIdx.x;
  if (i < n) p[i] = 0.f;
}

// ---------------- CSR build ----------------
__global__ void count_edges(const int* __restrict__ edges, int* __restrict__ counts) {
  int i = blockIdx.x * 256 + threadIdx.x;
  if (i >= NETOT) return;
  int dst = (i < NEDGE) ? edges[NEDGE + i] : (i - NEDGE);
  atomicAdd(&counts[dst], 1);
}

// hierarchical scan: a) per-block inclusive scan + block sums
__global__ void scan_a(const int* __restrict__ counts, int* __restrict__ lscan,
                       int* __restrict__ bsum) {
  __shared__ int sh[256];
  int t = threadIdx.x;
  int i = blockIdx.x * 256 + t;
  int v = (i < NNODES) ? counts[i] : 0;
  sh[t] = v;
  __syncthreads();
  for (int d = 1; d < 256; d <<= 1) {
    int add = (t >= d) ? sh[t - d] : 0;
    __syncthreads();
    sh[t] += add;
    __syncthreads();
  }
  lscan[i] = sh[t];
  if (t == 255) bsum[blockIdx.x] = sh[255];
}
// b) scan the 79 block sums (exclusive)
__global__ void scan_b(const int* __restrict__ bsum, int* __restrict__ bbase) {
  __shared__ int sh[128];
  int t = threadIdx.x;
  int v = (t < NSCANB) ? bsum[t] : 0;
  sh[t] = v;
  __syncthreads();
  for (int d = 1; d < 128; d <<= 1) {
    int add = (t >= d) ? sh[t - d] : 0;
    __syncthreads();
    sh[t] += add;
    __syncthreads();
  }
  if (t < NSCANB) bbase[t] = sh[t] - v;
}
// c) combine -> offsets, cursor
__global__ void scan_c(const int* __restrict__ lscan, const int* __restrict__ counts,
                       const int* __restrict__ bbase, int* __restrict__ offsets,
                       int* __restrict__ cursor) {
  int t = threadIdx.x;
  int i = blockIdx.x * 256 + t;
  if (i == 0) offsets[0] = 0;
  if (i < NNODES) {
    int incl = lscan[i] + bbase[blockIdx.x];
    offsets[i + 1] = incl;
    cursor[i] = incl - counts[i];
  }
}

__global__ void fill_edges(const int* __restrict__ edges, int* __restrict__ cursor,
                           int* __restrict__ csr_src) {
  int i = blockIdx.x * 256 + threadIdx.x;
  if (i >= NETOT) return;
  int src, dst;
  if (i < NEDGE) { src = edges[i]; dst = edges[NEDGE + i]; }
  else { src = dst = i - NEDGE; }
  int pos = atomicAdd(&cursor[dst], 1);
  csr_src[pos] = src;
}

// ---------------- layer 0 embed (tile(x,(1,2)) folded), f32 in -> bf16 out ----------------
__global__ void embed0(const float* __restrict__ cons, const float* __restrict__ cols,
                       const float* __restrict__ nW, const float* __restrict__ nb,
                       const float* __restrict__ cW, const float* __restrict__ cb,
                       u16* __restrict__ emb) {
  int idx = blockIdx.x * 256 + threadIdx.x;
  if (idx >= NNODES * 128) return;
  int row = idx >> 7, o = idx & 127;
  float acc;
  if (row < NCONS) {
    acc = nb[o];
    #pragma unroll
    for (int k = 0; k < 4; ++k)
      acc += cons[row * 4 + k] * (nW[o * 8 + k] + nW[o * 8 + 4 + k]);
  } else {
    int r = row - NCONS;
    acc = cb[o];
    #pragma unroll
    for (int k = 0; k < 8; ++k)
      acc += cols[r * 8 + k] * (cW[o * 16 + k] + cW[o * 16 + 8 + k]);
  }
  emb[idx] = f2bf(fmaxf(acc, 0.f));
}

// ---------------- GEMM: C[M,N] = A[M,K] @ B[N,K]^T, bf16 in ----------------
// block 256 = 4 waves; block tile 64(M)x64(N); each wave: 16(M)x64(N)
// DOTS: fused attention-dot partial reduction + atomicAdd into a_src/a_dst [M, N/128]
// HM:   store C head-major: C[(col>>7)][row][col&127] with row stride 128, slice NNODES*128
template <bool DOTS, bool HM, bool BIAS, bool OUTF32>
__global__ __launch_bounds__(256) void gemm_bt(const u16* __restrict__ A, const u16* __restrict__ B,
                                               const float* __restrict__ bias, void* __restrict__ Cv,
                                               const float* __restrict__ att_s,
                                               const float* __restrict__ att_d,
                                               float* __restrict__ a_srcO, float* __restrict__ a_dstO,
                                               int M, int N, int K) {
  int wave = threadIdx.x >> 6;
  int lane = threadIdx.x & 63;
  int quad = lane >> 4;
  int m0 = blockIdx.x * 64 + wave * 16;
  int n0 = blockIdx.y * 64;
  int row0 = m0 + (lane & 15);
  int rr = row0 < M ? row0 : M - 1;   // clamp loads; stores guarded
  f32x4 acc[4] = {f32x4{0,0,0,0}, f32x4{0,0,0,0}, f32x4{0,0,0,0}, f32x4{0,0,0,0}};
  for (int k0 = 0; k0 < K; k0 += 32) {
    bf16x8 a = *(const bf16x8*)(A + (size_t)rr * K + k0 + quad * 8);
    #pragma unroll
    for (int ns = 0; ns < 4; ++ns) {
      int col = n0 + ns * 16 + (lane & 15);
      bf16x8 b = *(const bf16x8*)(B + (size_t)col * K + k0 + quad * 8);
      acc[ns] = __builtin_amdgcn_mfma_f32_16x16x32_bf16(a, b, acc[ns], 0, 0, 0);
    }
  }
  int h = n0 >> 7;                     // constant over the 64-col tile
  if (DOTS) {
    float av_s[4], av_d[4];
    #pragma unroll
    for (int ns = 0; ns < 4; ++ns) {
      int col = n0 + ns * 16 + (lane & 15);
      av_s[ns] = att_s[col];
      av_d[ns] = att_d[col];
    }
    int H = N >> 7;
    #pragma unroll
    for (int r = 0; r < 4; ++r) {
      float sp = 0.f, dp = 0.f;
      #pragma unroll
      for (int ns = 0; ns < 4; ++ns) {
        sp += acc[ns][r] * av_s[ns];
        dp += acc[ns][r] * av_d[ns];
      }
      #pragma unroll
      for (int w = 1; w < 16; w <<= 1) {   // butterfly within 16-lane quad group
        sp += __shfl_xor(sp, w, 64);
        dp += __shfl_xor(dp, w, 64);
      }
      int orow = m0 + quad * 4 + r;
      if ((lane & 15) == 0 && orow < M) {
        atomicAdd(&a_srcO[(size_t)orow * H + h], sp);
        atomicAdd(&a_dstO[(size_t)orow * H + h], dp);
      }
    }
  }
  #pragma unroll
  for (int ns = 0; ns < 4; ++ns) {
    int col = n0 + ns * 16 + (lane & 15);
    float bv = BIAS ? bias[col] : 0.f;
    #pragma unroll
    for (int r = 0; r < 4; ++r) {
      int orow = m0 + quad * 4 + r;
      if (orow < M) {
        float v = acc[ns][r] + bv;
        if (OUTF32) {
          ((float*)Cv)[(size_t)orow * N + col] = v;
        } else if (HM) {
          ((u16*)Cv)[(size_t)h * ((size_t)NNODES * 128) + (size_t)orow * 128 + (col & 127)] = f2bf(v);
        } else {
          ((u16*)Cv)[(size_t)orow * N + col] = f2bf(v);
        }
      }
    }
  }
}

// ---------------- alpha (softmax weights) per edge, CSR-ordered ----------------
// layer1 (H=8): one wave per dst; lane = h*8+i, i strides edges. head-major out [8][NETOT]
__global__ __launch_bounds__(256) void alpha1_k(const int* __restrict__ offs,
                                                const int* __restrict__ csr_src,
                                                const float* __restrict__ a_src,
                                                const float* __restrict__ a_dst,
                                                float* __restrict__ alpha) {
  int wv = threadIdx.x >> 6;
  int dst = blockIdx.x * 4 + wv;
  if (dst >= NNODES) return;
  int l = threadIdx.x & 63;
  int h = l >> 3, i = l & 7;
  int off = offs[dst];
  int deg = offs[dst + 1] - off;
  float ad = a_dst[dst * 8 + h];
  float m = -1e30f, ssum = 0.f;
  for (int j = i; j < deg; j += 8) {
    int s = csr_src[off + j];
    float e = lrelu(a_src[s * 8 + h] + ad);
    float nm = fmaxf(m, e);
    ssum = ssum * __expf(m - nm) + __expf(e - nm);
    m = nm;
  }
  #pragma unroll
  for (int w = 1; w < 8; w <<= 1) {
    float om = __shfl_xor(m, w, 64);
    float os = __shfl_xor(ssum, w, 64);
    float nm = fmaxf(m, om);
    ssum = ssum * __expf(m - nm) + os * __expf(om - nm);
    m = nm;
  }
  float inv = 1.f / (ssum + 1e-16f);
  float* out = alpha + (size_t)h * NETOT;
  for (int j = i; j < deg; j += 8) {
    int s = csr_src[off + j];
    float e = lrelu(a_src[s * 8 + h] + ad);
    out[off + j] = __expf(e - m) * inv;
  }
}

// layer2 (H=1): one wave per dst, all 64 lanes stride edges
__global__ __launch_bounds__(256) void alpha2_k(const int* __restrict__ offs,
                                                const int* __restrict__ csr_src,
                                                const float* __restrict__ a_src,
                                                const float* __restrict__ a_dst,
                                                float* __restrict__ alpha) {
  int wv = threadIdx.x >> 6;
  int dst = blockIdx.x * 4 + wv;
  if (dst >= NNODES) return;
  int l = threadIdx.x & 63;
  int off = offs[dst];
  int deg = offs[dst + 1] - off;
  float ad = a_dst[dst];
  float m = -1e30f, ssum = 0.f;
  for (int j = l; j < deg; j += 64) {
    int s = csr_src[off + j];
    float e = lrelu(a_src[s] + ad);
    float nm = fmaxf(m, e);
    ssum = ssum * __expf(m - nm) + __expf(e - nm);
    m = nm;
  }
  #pragma unroll
  for (int w = 1; w < 64; w <<= 1) {
    float om = __shfl_xor(m, w, 64);
    float os = __shfl_xor(ssum, w, 64);
    float nm = fmaxf(m, om);
    ssum = ssum * __expf(m - nm) + os * __expf(om - nm);
    m = nm;
  }
  float inv = 1.f / (ssum + 1e-16f);
  for (int j = l; j < deg; j += 64) {
    int s = csr_src[off + j];
    float e = lrelu(a_src[s] + ad);
    alpha[off + j] = __expf(e - m) * inv;
  }
}

// ---------------- SpMM layer1: emb2[dst, h*128+c] = relu(sum_e alpha*xp1h[h][src][c] + b1) --------
// grid 8*5000 blocks of 256 (4 waves = 4 dsts, same head). h = blockIdx.x % 8 -> XCD affinity.
__global__ __launch_bounds__(256) void spmm1(const int* __restrict__ offs,
                                             const int* __restrict__ csr_src,
                                             const float* __restrict__ alpha,
                                             const u16* __restrict__ xp1h,
                                             const float* __restrict__ bias,
                                             u16* __restrict__ out) {
  int lin = blockIdx.x;
  int h = lin & 7;
  int wv = threadIdx.x >> 6;
  int dst = (lin >> 3) * 4 + wv;
  if (dst >= NNODES) return;
  int l = threadIdx.x & 63;
  int off = offs[dst];
  int deg = offs[dst + 1] - off;
  const float* al = alpha + (size_t)h * NETOT + off;
  const int* srcs = csr_src + off;
  const u16* base = xp1h + (size_t)h * ((size_t)NNODES * 128) + l * 2;
  float a0 = 0.f, a1 = 0.f;
  int j = 0;
  for (; j + 1 < deg; j += 2) {
    int s0 = srcs[j], s1 = srcs[j + 1];
    float w0 = al[j], w1 = al[j + 1];
    ushort2 u0 = *(const ushort2*)(base + (size_t)s0 * 128);
    ushort2 u1 = *(const ushort2*)(base + (size_t)s1 * 128);
    a0 += w0 * bf2f(u0.x) + w1 * bf2f(u1.x);
    a1 += w0 * bf2f(u0.y) + w1 * bf2f(u1.y);
  }
  if (j < deg) {
    int s0 = srcs[j];
    float w0 = al[j];
    ushort2 u0 = *(const ushort2*)(base + (size_t)s0 * 128);
    a0 += w0 * bf2f(u0.x);
    a1 += w0 * bf2f(u0.y);
  }
  int c = h * 128 + l * 2;
  ushort2 o;
  o.x = f2bf(fmaxf(a0 + bias[c], 0.f));
  o.y = f2bf(fmaxf(a1 + bias[c + 1], 0.f));
  *(ushort2*)(out + (size_t)dst * 1024 + c) = o;
}

// ---------------- SpMM layer2 (H=1, C=128): emb3 = relu(agg + b2) ----------------
__global__ __launch_bounds__(256) void spmm2(const int* __restrict__ offs,
                                             const int* __restrict__ csr_src,
                                             const float* __restrict__ alpha,
                                             const u16* __restrict__ xp2,
                                             const float* __restrict__ bias,
                                             u16* __restrict__ out) {
  int wv = threadIdx.x >> 6;
  int dst = blockIdx.x * 4 + wv;
  if (dst >= NNODES) return;
  int l = threadIdx.x & 63;
  int off = offs[dst];
  int deg = offs[dst + 1] - off;
  const float* al = alpha + off;
  const int* srcs = csr_src + off;
  const u16* base = xp2 + l * 2;
  float a0 = 0.f, a1 = 0.f;
  int j = 0;
  for (; j + 1 < deg; j += 2) {
    int s0 = srcs[j], s1 = srcs[j + 1];
    float w0 = al[j], w1 = al[j + 1];
    ushort2 u0 = *(const ushort2*)(base + (size_t)s0 * 128);
    ushort2 u1 = *(const ushort2*)(base + (size_t)s1 * 128);
    a0 += w0 * bf2f(u0.x) + w1 * bf2f(u1.x);
    a1 += w0 * bf2f(u0.y) + w1 * bf2f(u1.y);
  }
  if (j < deg) {
    int s0 = srcs[j];
    float w0 = al[j];
    ushort2 u0 = *(const ushort2*)(base + (size_t)s0 * 128);
    a0 += w0 * bf2f(u0.x);
    a1 += w0 * bf2f(u0.y);
  }
  int c = l * 2;
  ushort2 o;
  o.x = f2bf(fmaxf(a0 + bias[c], 0.f));
  o.y = f2bf(fmaxf(a1 + bias[c + 1], 0.f));
  *(ushort2*)(out + (size_t)dst * 128 + c) = o;
}

// ---------------- launch ----------------
extern "C" void kernel_launch(void* const* d_in, const int* in_sizes, int n_in,
                              void* d_out, int out_size, void* d_ws, size_t ws_size,
                              hipStream_t stream) {
  const float* cons    = (const float*)d_in[0];
  const float* cols    = (const float*)d_in[1];
  const float* node_W  = (const float*)d_in[2];
  const float* node_b  = (const float*)d_in[3];
  const float* col_W   = (const float*)d_in[4];
  const float* col_b   = (const float*)d_in[5];
  const float* W1      = (const float*)d_in[6];
  const float* att_s1  = (const float*)d_in[7];
  const float* att_d1  = (const float*)d_in[8];
  const float* b1      = (const float*)d_in[9];
  const float* W2      = (const float*)d_in[10];
  const float* att_s2  = (const float*)d_in[11];
  const float* att_d2  = (const float*)d_in[12];
  const float* b2      = (const float*)d_in[13];
  const float* out_W   = (const float*)d_in[14];
  const float* out_b   = (const float*)d_in[15];
  const int* edges     = (const int*)d_in[16];

  char* p = (char*)d_ws;
  auto alloc = [&](size_t bytes) {
    char* r = p;
    p += (bytes + 255) & ~(size_t)255;
    return r;
  };
  u16* emb0    = (u16*)alloc((size_t)NNODES * 128 * 2);        // bf16
  u16* xp1h    = (u16*)alloc((size_t)8 * NNODES * 128 * 2);    // bf16, head-major
  u16* emb2    = (u16*)alloc((size_t)NNODES * 1024 * 2);       // bf16
  u16* xp2     = (u16*)alloc((size_t)NNODES * 128 * 2);        // bf16
  u16* emb3    = (u16*)alloc((size_t)NNODES * 128 * 2);        // bf16
  u16* W1bf    = (u16*)alloc((size_t)1024 * 128 * 2);
  u16* W2bf    = (u16*)alloc((size_t)128 * 1024 * 2);
  u16* oWbf    = (u16*)alloc((size_t)128 * 128 * 2);
  float* as1   = (float*)alloc((size_t)NNODES * 8 * 4);        // contiguous zero region start
  float* ad1   = (float*)alloc((size_t)NNODES * 8 * 4);
  float* as2   = (float*)alloc((size_t)NNODES * 4);
  float* ad2   = (float*)alloc((size_t)NNODES * 4);
  float* alp1  = (float*)alloc((size_t)8 * NETOT * 4);         // head-major [8][NETOT]
  float* alp2  = (float*)alloc((size_t)NETOT * 4);
  int* counts  = (int*)alloc((size_t)NNODES * 4);
  int* offs    = (int*)alloc((size_t)(NNODES + 1) * 4);
  int* cursor  = (int*)alloc((size_t)NNODES * 4);
  int* csrsrc  = (int*)alloc((size_t)NETOT * 4);
  int* lscan   = (int*)alloc((size_t)NSCANB * 256 * 4);
  int* bsum    = (int*)alloc((size_t)NSCANB * 4);
  int* bbase   = (int*)alloc((size_t)NSCANB * 4);

  // zero counts + the four atomic-dot accumulators (as1,ad1,as2,ad2 contiguous-ish)
  zero_i32<<<(NNODES + 255) / 256, 256, 0, stream>>>(counts, NNODES);
  zero_f32<<<(NNODES * 18 + 255) / 256, 256, 0, stream>>>(as1, NNODES * 18);  // 8+8+1+1 floats per node

  // CSR build
  count_edges<<<(NETOT + 255) / 256, 256, 0, stream>>>(edges, counts);
  scan_a<<<NSCANB, 256, 0, stream>>>(counts, lscan, bsum);
  scan_b<<<1, 128, 0, stream>>>(bsum, bbase);
  scan_c<<<NSCANB, 256, 0, stream>>>(lscan, counts, bbase, offs, cursor);
  fill_edges<<<(NETOT + 255) / 256, 256, 0, stream>>>(edges, cursor, csrsrc);

  // weight conversions f32 -> bf16
  cvt_bf16<<<(1024 * 128 + 255) / 256, 256, 0, stream>>>(W1, W1bf, 1024 * 128);
  cvt_bf16<<<(128 * 1024 + 255) / 256, 256, 0, stream>>>(W2, W2bf, 128 * 1024);
  cvt_bf16<<<(128 * 128 + 255) / 256, 256, 0, stream>>>(out_W, oWbf, 128 * 128);

  // layer 0 embed
  embed0<<<(NNODES * 128 + 255) / 256, 256, 0, stream>>>(cons, cols, node_W, node_b,
                                                         col_W, col_b, emb0);

  // GAT layer 1: GEMM (fused dots, head-major out) -> alpha -> SpMM
  gemm_bt<true, true, false, false><<<dim3((NNODES + 63) / 64, 1024 / 64), 256, 0, stream>>>(
      emb0, W1bf, nullptr, xp1h, att_s1, att_d1, as1, ad1, NNODES, 1024, 128);
  alpha1_k<<<(NNODES + 3) / 4, 256, 0, stream>>>(offs, csrsrc, as1, ad1, alp1);
  spmm1<<<8 * ((NNODES + 3) / 4), 256, 0, stream>>>(offs, csrsrc, alp1, xp1h, b1, emb2);

  // GAT layer 2: GEMM (fused dots) -> alpha -> SpMM
  gemm_bt<true, false, false, false><<<dim3((NNODES + 63) / 64, 128 / 64), 256, 0, stream>>>(
      emb2, W2bf, nullptr, xp2, att_s2, att_d2, as2, ad2, NNODES, 128, 1024);
  alpha2_k<<<(NNODES + 3) / 4, 256, 0, stream>>>(offs, csrsrc, as2, ad2, alp2);
  spmm2<<<(NNODES + 3) / 4, 256, 0, stream>>>(offs, csrsrc, alp2, xp2, b2, emb3);

  // output projection: rows 10000..19999, f32 out with bias
  gemm_bt<false, false, true, true><<<dim3((NCOLSN + 63) / 64, 128 / 64), 256, 0, stream>>>(
      emb3 + (size_t)NCONS * 128, oWbf, out_b, d_out, nullptr, nullptr, nullptr, nullptr,
      NCOLSN, 128, 128);
}

// Round 4
// 386.348 us; speedup vs baseline: 1.2307x; 1.0838x over previous
//
#include <hip/hip_runtime.h>

// ---------------- problem constants ----------------
#define NCONS 10000
#define NCOLSN 10000
#define NNODES 20000         // NCONS + NCOLSN
#define NEDGE 200000
#define NETOT 220000         // NEDGE + NNODES self loops
#define NEG_SLOPE 0.2f
#define NSCANB 79            // ceil(NNODES/256)

typedef unsigned short u16;
typedef __attribute__((ext_vector_type(8))) short bf16x8;
typedef __attribute__((ext_vector_type(4))) float f32x4;

__device__ __forceinline__ float bf2f(u16 u) {
  return __uint_as_float(((unsigned int)u) << 16);
}
__device__ __forceinline__ u16 f2bf(float f) {
  unsigned int x = __float_as_uint(f);
  return (u16)((x + 0x7fffu + ((x >> 16) & 1u)) >> 16);
}
__device__ __forceinline__ float lrelu(float v) {
  return v >= 0.f ? v : NEG_SLOPE * v;
}

// ---------------- small utils ----------------
__global__ void cvt_bf16(const float* __restrict__ in, u16* __restrict__ out, int n) {
  int i = blockIdx.x * 256 + threadIdx.x;
  if (i < n) out[i] = f2bf(in[i]);
}
__global__ void zero_i32(int* p, int n) {
  int i = blockIdx.x * 256 + threadIdx.x;
  if (i < n) p[i] = 0;
}
__global__ void zero_f32(float* p, int n) {
  int i = blockIdx.x * 256 + threadIdx.x;
  if (i < n) p[i] = 0.f;
}

// ---------------- CSR build ----------------
__global__ void count_edges(const int* __restrict__ edges, int* __restrict__ counts) {
  int i = blockIdx.x * 256 + threadIdx.x;
  if (i >= NETOT) return;
  int dst = (i < NEDGE) ? edges[NEDGE + i] : (i - NEDGE);
  atomicAdd(&counts[dst], 1);
}

__global__ void scan_a(const int* __restrict__ counts, int* __restrict__ lscan,
                       int* __restrict__ bsum) {
  __shared__ int sh[256];
  int t = threadIdx.x;
  int i = blockIdx.x * 256 + t;
  int v = (i < NNODES) ? counts[i] : 0;
  sh[t] = v;
  __syncthreads();
  for (int d = 1; d < 256; d <<= 1) {
    int add = (t >= d) ? sh[t - d] : 0;
    __syncthreads();
    sh[t] += add;
    __syncthreads();
  }
  lscan[i] = sh[t];
  if (t == 255) bsum[blockIdx.x] = sh[255];
}
__global__ void scan_b(const int* __restrict__ bsum, int* __restrict__ bbase) {
  __shared__ int sh[128];
  int t = threadIdx.x;
  int v = (t < NSCANB) ? bsum[t] : 0;
  sh[t] = v;
  __syncthreads();
  for (int d = 1; d < 128; d <<= 1) {
    int add = (t >= d) ? sh[t - d] : 0;
    __syncthreads();
    sh[t] += add;
    __syncthreads();
  }
  if (t < NSCANB) bbase[t] = sh[t] - v;
}
__global__ void scan_c(const int* __restrict__ lscan, const int* __restrict__ counts,
                       const int* __restrict__ bbase, int* __restrict__ offsets,
                       int* __restrict__ cursor) {
  int t = threadIdx.x;
  int i = blockIdx.x * 256 + t;
  if (i == 0) offsets[0] = 0;
  if (i < NNODES) {
    int incl = lscan[i] + bbase[blockIdx.x];
    offsets[i + 1] = incl;
    cursor[i] = incl - counts[i];
  }
}

__global__ void fill_edges(const int* __restrict__ edges, int* __restrict__ cursor,
                           int* __restrict__ csr_src) {
  int i = blockIdx.x * 256 + threadIdx.x;
  if (i >= NETOT) return;
  int src, dst;
  if (i < NEDGE) { src = edges[i]; dst = edges[NEDGE + i]; }
  else { src = dst = i - NEDGE; }
  int pos = atomicAdd(&cursor[dst], 1);
  csr_src[pos] = src;
}

// ---------------- layer 0 embed (tile(x,(1,2)) folded), f32 in -> bf16 out ----------------
__global__ void embed0(const float* __restrict__ cons, const float* __restrict__ cols,
                       const float* __restrict__ nW, const float* __restrict__ nb,
                       const float* __restrict__ cW, const float* __restrict__ cb,
                       u16* __restrict__ emb) {
  int idx = blockIdx.x * 256 + threadIdx.x;
  if (idx >= NNODES * 128) return;
  int row = idx >> 7, o = idx & 127;
  float acc;
  if (row < NCONS) {
    acc = nb[o];
    #pragma unroll
    for (int k = 0; k < 4; ++k)
      acc += cons[row * 4 + k] * (nW[o * 8 + k] + nW[o * 8 + 4 + k]);
  } else {
    int r = row - NCONS;
    acc = cb[o];
    #pragma unroll
    for (int k = 0; k < 8; ++k)
      acc += cols[r * 8 + k] * (cW[o * 16 + k] + cW[o * 16 + 8 + k]);
  }
  emb[idx] = f2bf(fmaxf(acc, 0.f));
}

// ---------------- GEMM: C[M,N] = A[M,K] @ B[N,K]^T, bf16 in ----------------
// block 256 = 4 waves; block tile 64(M)x64(N); each wave: 16(M)x64(N)
// DOTS: fused attention-dot partial reduction + atomicAdd into a_src/a_dst [M, N/128]
// HM:   store C head-major: C[(col>>7)][row][col&127] with row stride 128, slice NNODES*128
template <bool DOTS, bool HM, bool BIAS, bool OUTF32>
__global__ __launch_bounds__(256) void gemm_bt(const u16* __restrict__ A, const u16* __restrict__ B,
                                               const float* __restrict__ bias, void* __restrict__ Cv,
                                               const float* __restrict__ att_s,
                                               const float* __restrict__ att_d,
                                               float* __restrict__ a_srcO, float* __restrict__ a_dstO,
                                               int M, int N, int K) {
  int wave = threadIdx.x >> 6;
  int lane = threadIdx.x & 63;
  int quad = lane >> 4;
  int m0 = blockIdx.x * 64 + wave * 16;
  int n0 = blockIdx.y * 64;
  int row0 = m0 + (lane & 15);
  int rr = row0 < M ? row0 : M - 1;   // clamp loads; stores guarded
  f32x4 acc[4] = {f32x4{0,0,0,0}, f32x4{0,0,0,0}, f32x4{0,0,0,0}, f32x4{0,0,0,0}};
  for (int k0 = 0; k0 < K; k0 += 32) {
    bf16x8 a = *(const bf16x8*)(A + (size_t)rr * K + k0 + quad * 8);
    #pragma unroll
    for (int ns = 0; ns < 4; ++ns) {
      int col = n0 + ns * 16 + (lane & 15);
      bf16x8 b = *(const bf16x8*)(B + (size_t)col * K + k0 + quad * 8);
      acc[ns] = __builtin_amdgcn_mfma_f32_16x16x32_bf16(a, b, acc[ns], 0, 0, 0);
    }
  }
  int h = n0 >> 7;                     // constant over the 64-col tile
  if (DOTS) {
    float av_s[4], av_d[4];
    #pragma unroll
    for (int ns = 0; ns < 4; ++ns) {
      int col = n0 + ns * 16 + (lane & 15);
      av_s[ns] = att_s[col];
      av_d[ns] = att_d[col];
    }
    int H = N >> 7;
    #pragma unroll
    for (int r = 0; r < 4; ++r) {
      float sp = 0.f, dp = 0.f;
      #pragma unroll
      for (int ns = 0; ns < 4; ++ns) {
        sp += acc[ns][r] * av_s[ns];
        dp += acc[ns][r] * av_d[ns];
      }
      #pragma unroll
      for (int w = 1; w < 16; w <<= 1) {   // butterfly within 16-lane quad group
        sp += __shfl_xor(sp, w, 64);
        dp += __shfl_xor(dp, w, 64);
      }
      int orow = m0 + quad * 4 + r;
      if ((lane & 15) == 0 && orow < M) {
        atomicAdd(&a_srcO[(size_t)orow * H + h], sp);
        atomicAdd(&a_dstO[(size_t)orow * H + h], dp);
      }
    }
  }
  #pragma unroll
  for (int ns = 0; ns < 4; ++ns) {
    int col = n0 + ns * 16 + (lane & 15);
    float bv = BIAS ? bias[col] : 0.f;
    #pragma unroll
    for (int r = 0; r < 4; ++r) {
      int orow = m0 + quad * 4 + r;
      if (orow < M) {
        float v = acc[ns][r] + bv;
        if (OUTF32) {
          ((float*)Cv)[(size_t)orow * N + col] = v;
        } else if (HM) {
          ((u16*)Cv)[(size_t)h * ((size_t)NNODES * 128) + (size_t)orow * 128 + (col & 127)] = f2bf(v);
        } else {
          ((u16*)Cv)[(size_t)orow * N + col] = f2bf(v);
        }
      }
    }
  }
}

// ---------------- alpha (softmax weights) per edge, CSR-ordered ----------------
// layer1 (H=8): one wave per dst; lane = i*8+h so 8 heads' a_src gathers coalesce (32 B).
// i = edge slot (8 in flight). head-major out [8][NETOT]
__global__ __launch_bounds__(256) void alpha1_k(const int* __restrict__ offs,
                                                const int* __restrict__ csr_src,
                                                const float* __restrict__ a_src,
                                                const float* __restrict__ a_dst,
                                                float* __restrict__ alpha) {
  int wv = threadIdx.x >> 6;
  int dst = blockIdx.x * 4 + wv;
  if (dst >= NNODES) return;
  int l = threadIdx.x & 63;
  int h = l & 7, i = l >> 3;
  int off = offs[dst];
  int deg = offs[dst + 1] - off;
  float ad = a_dst[dst * 8 + h];
  float m = -1e30f, ssum = 0.f;
  for (int j = i; j < deg; j += 8) {
    int s = csr_src[off + j];
    float e = lrelu(a_src[s * 8 + h] + ad);
    float nm = fmaxf(m, e);
    ssum = ssum * __expf(m - nm) + __expf(e - nm);
    m = nm;
  }
  #pragma unroll
  for (int w = 8; w < 64; w <<= 1) {    // reduce over i (stride-8 lanes)
    float om = __shfl_xor(m, w, 64);
    float os = __shfl_xor(ssum, w, 64);
    float nm = fmaxf(m, om);
    ssum = ssum * __expf(m - nm) + os * __expf(om - nm);
    m = nm;
  }
  float inv = 1.f / (ssum + 1e-16f);
  float* out = alpha + (size_t)h * NETOT;
  for (int j = i; j < deg; j += 8) {
    int s = csr_src[off + j];
    float e = lrelu(a_src[s * 8 + h] + ad);
    out[off + j] = __expf(e - m) * inv;
  }
}

// layer2 (H=1): one wave per dst, all 64 lanes stride edges
__global__ __launch_bounds__(256) void alpha2_k(const int* __restrict__ offs,
                                                const int* __restrict__ csr_src,
                                                const float* __restrict__ a_src,
                                                const float* __restrict__ a_dst,
                                                float* __restrict__ alpha) {
  int wv = threadIdx.x >> 6;
  int dst = blockIdx.x * 4 + wv;
  if (dst >= NNODES) return;
  int l = threadIdx.x & 63;
  int off = offs[dst];
  int deg = offs[dst + 1] - off;
  float ad = a_dst[dst];
  float m = -1e30f, ssum = 0.f;
  for (int j = l; j < deg; j += 64) {
    int s = csr_src[off + j];
    float e = lrelu(a_src[s] + ad);
    float nm = fmaxf(m, e);
    ssum = ssum * __expf(m - nm) + __expf(e - nm);
    m = nm;
  }
  #pragma unroll
  for (int w = 1; w < 64; w <<= 1) {
    float om = __shfl_xor(m, w, 64);
    float os = __shfl_xor(ssum, w, 64);
    float nm = fmaxf(m, om);
    ssum = ssum * __expf(m - nm) + os * __expf(om - nm);
    m = nm;
  }
  float inv = 1.f / (ssum + 1e-16f);
  for (int j = l; j < deg; j += 64) {
    int s = csr_src[off + j];
    float e = lrelu(a_src[s] + ad);
    alpha[off + j] = __expf(e - m) * inv;
  }
}

// ---------------- SpMM layer1 ----------------
// wave per (dst, head); lane = e*16 + c: 4 edge slots in flight, lane loads bf16x8 (16 B)
// of channels c*8..c*8+7. h = blockIdx.x % 8 -> XCD affinity on head slice.
__global__ __launch_bounds__(256) void spmm1(const int* __restrict__ offs,
                                             const int* __restrict__ csr_src,
                                             const float* __restrict__ alpha,
                                             const u16* __restrict__ xp1h,
                                             const float* __restrict__ bias,
                                             u16* __restrict__ out) {
  int lin = blockIdx.x;
  int h = lin & 7;
  int wv = threadIdx.x >> 6;
  int dst = (lin >> 3) * 4 + wv;
  if (dst >= NNODES) return;
  int l = threadIdx.x & 63;
  int e = l >> 4, c = l & 15;
  int off = offs[dst];
  int deg = offs[dst + 1] - off;
  const float* al = alpha + (size_t)h * NETOT + off;
  const int* srcs = csr_src + off;
  const u16* base = xp1h + (size_t)h * ((size_t)NNODES * 128) + c * 8;
  float acc[8] = {0.f, 0.f, 0.f, 0.f, 0.f, 0.f, 0.f, 0.f};
  for (int j = 0; j < deg; j += 4) {
    int je = j + e;
    bool val = je < deg;
    int idx = val ? je : deg - 1;      // deg>=1 (self-loop)
    int s = srcs[idx];
    float w = val ? al[idx] : 0.f;
    bf16x8 f = *(const bf16x8*)(base + (size_t)s * 128);
    #pragma unroll
    for (int k = 0; k < 8; ++k) acc[k] += w * bf2f((u16)f[k]);
  }
  #pragma unroll
  for (int k = 0; k < 8; ++k) {        // reduce over e (lane bits 4,5)
    acc[k] += __shfl_xor(acc[k], 16, 64);
    acc[k] += __shfl_xor(acc[k], 32, 64);
  }
  if (e == 0) {
    int cg = h * 128 + c * 8;
    union { u16 a[8]; uint4 v; } o;
    #pragma unroll
    for (int k = 0; k < 8; ++k) o.a[k] = f2bf(fmaxf(acc[k] + bias[cg + k], 0.f));
    *(uint4*)(out + (size_t)dst * 1024 + cg) = o.v;
  }
}

// ---------------- SpMM layer2 (H=1, C=128) ----------------
__global__ __launch_bounds__(256) void spmm2(const int* __restrict__ offs,
                                             const int* __restrict__ csr_src,
                                             const float* __restrict__ alpha,
                                             const u16* __restrict__ xp2,
                                             const float* __restrict__ bias,
                                             u16* __restrict__ out) {
  int wv = threadIdx.x >> 6;
  int dst = blockIdx.x * 4 + wv;
  if (dst >= NNODES) return;
  int l = threadIdx.x & 63;
  int e = l >> 4, c = l & 15;
  int off = offs[dst];
  int deg = offs[dst + 1] - off;
  const float* al = alpha + off;
  const int* srcs = csr_src + off;
  const u16* base = xp2 + c * 8;
  float acc[8] = {0.f, 0.f, 0.f, 0.f, 0.f, 0.f, 0.f, 0.f};
  for (int j = 0; j < deg; j += 4) {
    int je = j + e;
    bool val = je < deg;
    int idx = val ? je : deg - 1;
    int s = srcs[idx];
    float w = val ? al[idx] : 0.f;
    bf16x8 f = *(const bf16x8*)(base + (size_t)s * 128);
    #pragma unroll
    for (int k = 0; k < 8; ++k) acc[k] += w * bf2f((u16)f[k]);
  }
  #pragma unroll
  for (int k = 0; k < 8; ++k) {
    acc[k] += __shfl_xor(acc[k], 16, 64);
    acc[k] += __shfl_xor(acc[k], 32, 64);
  }
  if (e == 0) {
    int cg = c * 8;
    union { u16 a[8]; uint4 v; } o;
    #pragma unroll
    for (int k = 0; k < 8; ++k) o.a[k] = f2bf(fmaxf(acc[k] + bias[cg + k], 0.f));
    *(uint4*)(out + (size_t)dst * 128 + cg) = o.v;
  }
}

// ---------------- launch ----------------
extern "C" void kernel_launch(void* const* d_in, const int* in_sizes, int n_in,
                              void* d_out, int out_size, void* d_ws, size_t ws_size,
                              hipStream_t stream) {
  const float* cons    = (const float*)d_in[0];
  const float* cols    = (const float*)d_in[1];
  const float* node_W  = (const float*)d_in[2];
  const float* node_b  = (const float*)d_in[3];
  const float* col_W   = (const float*)d_in[4];
  const float* col_b   = (const float*)d_in[5];
  const float* W1      = (const float*)d_in[6];
  const float* att_s1  = (const float*)d_in[7];
  const float* att_d1  = (const float*)d_in[8];
  const float* b1      = (const float*)d_in[9];
  const float* W2      = (const float*)d_in[10];
  const float* att_s2  = (const float*)d_in[11];
  const float* att_d2  = (const float*)d_in[12];
  const float* b2      = (const float*)d_in[13];
  const float* out_W   = (const float*)d_in[14];
  const float* out_b   = (const float*)d_in[15];
  const int* edges     = (const int*)d_in[16];

  char* p = (char*)d_ws;
  auto alloc = [&](size_t bytes) {
    char* r = p;
    p += (bytes + 255) & ~(size_t)255;
    return r;
  };
  u16* emb0    = (u16*)alloc((size_t)NNODES * 128 * 2);        // bf16
  u16* xp1h    = (u16*)alloc((size_t)8 * NNODES * 128 * 2);    // bf16, head-major
  u16* emb2    = (u16*)alloc((size_t)NNODES * 1024 * 2);       // bf16
  u16* xp2     = (u16*)alloc((size_t)NNODES * 128 * 2);        // bf16
  u16* emb3    = (u16*)alloc((size_t)NNODES * 128 * 2);        // bf16
  u16* W1bf    = (u16*)alloc((size_t)1024 * 128 * 2);
  u16* W2bf    = (u16*)alloc((size_t)128 * 1024 * 2);
  u16* oWbf    = (u16*)alloc((size_t)128 * 128 * 2);
  float* as1   = (float*)alloc((size_t)NNODES * 8 * 4);        // zero region start
  float* ad1   = (float*)alloc((size_t)NNODES * 8 * 4);
  float* as2   = (float*)alloc((size_t)NNODES * 4);            // pads to 80128 B
  float* ad2   = (float*)alloc((size_t)NNODES * 4);
  float* alp1  = (float*)alloc((size_t)8 * NETOT * 4);         // head-major [8][NETOT]
  float* alp2  = (float*)alloc((size_t)NETOT * 4);
  int* counts  = (int*)alloc((size_t)NNODES * 4);
  int* offs    = (int*)alloc((size_t)(NNODES + 1) * 4);
  int* cursor  = (int*)alloc((size_t)NNODES * 4);
  int* csrsrc  = (int*)alloc((size_t)NETOT * 4);
  int* lscan   = (int*)alloc((size_t)NSCANB * 256 * 4);
  int* bsum    = (int*)alloc((size_t)NSCANB * 4);
  int* bbase   = (int*)alloc((size_t)NSCANB * 4);

  // zero counts + the four atomic-dot accumulators.
  // as1..ad2 region includes 256-B alloc padding: 640000+640000+80128+80128 bytes
  const int NZF = (640000 + 640000 + 80128 + 80128) / 4;
  zero_i32<<<(NNODES + 255) / 256, 256, 0, stream>>>(counts, NNODES);
  zero_f32<<<(NZF + 255) / 256, 256, 0, stream>>>(as1, NZF);

  // CSR build
  count_edges<<<(NETOT + 255) / 256, 256, 0, stream>>>(edges, counts);
  scan_a<<<NSCANB, 256, 0, stream>>>(counts, lscan, bsum);
  scan_b<<<1, 128, 0, stream>>>(bsum, bbase);
  scan_c<<<NSCANB, 256, 0, stream>>>(lscan, counts, bbase, offs, cursor);
  fill_edges<<<(NETOT + 255) / 256, 256, 0, stream>>>(edges, cursor, csrsrc);

  // weight conversions f32 -> bf16
  cvt_bf16<<<(1024 * 128 + 255) / 256, 256, 0, stream>>>(W1, W1bf, 1024 * 128);
  cvt_bf16<<<(128 * 1024 + 255) / 256, 256, 0, stream>>>(W2, W2bf, 128 * 1024);
  cvt_bf16<<<(128 * 128 + 255) / 256, 256, 0, stream>>>(out_W, oWbf, 128 * 128);

  // layer 0 embed
  embed0<<<(NNODES * 128 + 255) / 256, 256, 0, stream>>>(cons, cols, node_W, node_b,
                                                         col_W, col_b, emb0);

  // GAT layer 1: GEMM (fused dots, head-major out) -> alpha -> SpMM
  gemm_bt<true, true, false, false><<<dim3((NNODES + 63) / 64, 1024 / 64), 256, 0, stream>>>(
      emb0, W1bf, nullptr, xp1h, att_s1, att_d1, as1, ad1, NNODES, 1024, 128);
  alpha1_k<<<(NNODES + 3) / 4, 256, 0, stream>>>(offs, csrsrc, as1, ad1, alp1);
  spmm1<<<8 * ((NNODES + 3) / 4), 256, 0, stream>>>(offs, csrsrc, alp1, xp1h, b1, emb2);

  // GAT layer 2: GEMM (fused dots) -> alpha -> SpMM
  gemm_bt<true, false, false, false><<<dim3((NNODES + 63) / 64, 128 / 64), 256, 0, stream>>>(
      emb2, W2bf, nullptr, xp2, att_s2, att_d2, as2, ad2, NNODES, 128, 1024);
  alpha2_k<<<(NNODES + 3) / 4, 256, 0, stream>>>(offs, csrsrc, as2, ad2, alp2);
  spmm2<<<(NNODES + 3) / 4, 256, 0, stream>>>(offs, csrsrc, alp2, xp2, b2, emb3);

  // output projection: rows 10000..19999, f32 out with bias
  gemm_bt<false, false, true, true><<<dim3((NCOLSN + 63) / 64, 128 / 64), 256, 0, stream>>>(
      emb3 + (size_t)NCONS * 128, oWbf, out_b, d_out, nullptr, nullptr, nullptr, nullptr,
      NCOLSN, 128, 128);
}

// Round 5
// 367.911 us; speedup vs baseline: 1.2924x; 1.0501x over previous
//
#include <hip/hip_runtime.h>

// ---------------- problem constants ----------------
#define NCONS 10000
#define NCOLSN 10000
#define NNODES 20000         // NCONS + NCOLSN
#define NEDGE 200000
#define NETOT 220000         // NEDGE + NNODES self loops
#define NEG_SLOPE 0.2f
#define NSCANB 79            // ceil(NNODES/256)

typedef unsigned short u16;
typedef __attribute__((ext_vector_type(8))) short bf16x8;
typedef __attribute__((ext_vector_type(4))) float f32x4;

__device__ __forceinline__ float bf2f(u16 u) {
  return __uint_as_float(((unsigned int)u) << 16);
}
__device__ __forceinline__ u16 f2bf(float f) {
  unsigned int x = __float_as_uint(f);
  return (u16)((x + 0x7fffu + ((x >> 16) & 1u)) >> 16);
}
__device__ __forceinline__ float lrelu(float v) {
  return v >= 0.f ? v : NEG_SLOPE * v;
}

// ---------------- fused weight conversion f32->bf16 (W1|W2|out_W into contiguous dst) --------
#define W1N (1024 * 128)
#define W2N (128 * 1024)
#define OWN (128 * 128)
__global__ void cvt_all(const float* __restrict__ W1, const float* __restrict__ W2,
                        const float* __restrict__ oW, u16* __restrict__ out) {
  int i = blockIdx.x * 256 + threadIdx.x;
  if (i >= W1N + W2N + OWN) return;
  float v;
  if (i < W1N) v = W1[i];
  else if (i < W1N + W2N) v = W2[i - W1N];
  else v = oW[i - W1N - W2N];
  out[i] = f2bf(v);
}

// ---------------- CSR build ----------------
__global__ void count_edges(const int* __restrict__ edges, int* __restrict__ counts) {
  int i = blockIdx.x * 256 + threadIdx.x;
  if (i >= NETOT) return;
  int dst = (i < NEDGE) ? edges[NEDGE + i] : (i - NEDGE);
  atomicAdd(&counts[dst], 1);
}

__global__ void scan_a(const int* __restrict__ counts, int* __restrict__ lscan,
                       int* __restrict__ bsum) {
  __shared__ int sh[256];
  int t = threadIdx.x;
  int i = blockIdx.x * 256 + t;
  int v = (i < NNODES) ? counts[i] : 0;
  sh[t] = v;
  __syncthreads();
  for (int d = 1; d < 256; d <<= 1) {
    int add = (t >= d) ? sh[t - d] : 0;
    __syncthreads();
    sh[t] += add;
    __syncthreads();
  }
  lscan[i] = sh[t];
  if (t == 255) bsum[blockIdx.x] = sh[255];
}
__global__ void scan_b(const int* __restrict__ bsum, int* __restrict__ bbase) {
  __shared__ int sh[128];
  int t = threadIdx.x;
  int v = (t < NSCANB) ? bsum[t] : 0;
  sh[t] = v;
  __syncthreads();
  for (int d = 1; d < 128; d <<= 1) {
    int add = (t >= d) ? sh[t - d] : 0;
    __syncthreads();
    sh[t] += add;
    __syncthreads();
  }
  if (t < NSCANB) bbase[t] = sh[t] - v;
}
__global__ void scan_c(const int* __restrict__ lscan, const int* __restrict__ counts,
                       const int* __restrict__ bbase, int* __restrict__ offsets,
                       int* __restrict__ cursor) {
  int t = threadIdx.x;
  int i = blockIdx.x * 256 + t;
  if (i == 0) offsets[0] = 0;
  if (i < NNODES) {
    int incl = lscan[i] + bbase[blockIdx.x];
    offsets[i + 1] = incl;
    cursor[i] = incl - counts[i];
  }
}

__global__ void fill_edges(const int* __restrict__ edges, int* __restrict__ cursor,
                           int* __restrict__ csr_src) {
  int i = blockIdx.x * 256 + threadIdx.x;
  if (i >= NETOT) return;
  int src, dst;
  if (i < NEDGE) { src = edges[i]; dst = edges[NEDGE + i]; }
  else { src = dst = i - NEDGE; }
  int pos = atomicAdd(&cursor[dst], 1);
  csr_src[pos] = src;
}

// ---------------- layer 0 embed (tile(x,(1,2)) folded), f32 in -> bf16 out ----------------
__global__ void embed0(const float* __restrict__ cons, const float* __restrict__ cols,
                       const float* __restrict__ nW, const float* __restrict__ nb,
                       const float* __restrict__ cW, const float* __restrict__ cb,
                       u16* __restrict__ emb) {
  int idx = blockIdx.x * 256 + threadIdx.x;
  if (idx >= NNODES * 128) return;
  int row = idx >> 7, o = idx & 127;
  float acc;
  if (row < NCONS) {
    acc = nb[o];
    #pragma unroll
    for (int k = 0; k < 4; ++k)
      acc += cons[row * 4 + k] * (nW[o * 8 + k] + nW[o * 8 + 4 + k]);
  } else {
    int r = row - NCONS;
    acc = cb[o];
    #pragma unroll
    for (int k = 0; k < 8; ++k)
      acc += cols[r * 8 + k] * (cW[o * 16 + k] + cW[o * 16 + 8 + k]);
  }
  emb[idx] = f2bf(fmaxf(acc, 0.f));
}

// ---------------- GEMM: C[M,N] = A[M,K] @ B[N,K]^T, bf16 in ----------------
// block 256 = 4 waves; block tile 64(M)x64(N); each wave: 16(M)x64(N)
// DOTS: fused attention-dot partial reduction + atomicAdd into a_src/a_dst [M, N/128]
// HM:   store C head-major: C[(col>>7)][row][col&127] with row stride 128, slice NNODES*128
template <bool DOTS, bool HM, bool BIAS, bool OUTF32>
__global__ __launch_bounds__(256) void gemm_bt(const u16* __restrict__ A, const u16* __restrict__ B,
                                               const float* __restrict__ bias, void* __restrict__ Cv,
                                               const float* __restrict__ att_s,
                                               const float* __restrict__ att_d,
                                               float* __restrict__ a_srcO, float* __restrict__ a_dstO,
                                               int M, int N, int K) {
  int wave = threadIdx.x >> 6;
  int lane = threadIdx.x & 63;
  int quad = lane >> 4;
  int m0 = blockIdx.x * 64 + wave * 16;
  int n0 = blockIdx.y * 64;
  int row0 = m0 + (lane & 15);
  int rr = row0 < M ? row0 : M - 1;   // clamp loads; stores guarded
  f32x4 acc[4] = {f32x4{0,0,0,0}, f32x4{0,0,0,0}, f32x4{0,0,0,0}, f32x4{0,0,0,0}};
  for (int k0 = 0; k0 < K; k0 += 32) {
    bf16x8 a = *(const bf16x8*)(A + (size_t)rr * K + k0 + quad * 8);
    #pragma unroll
    for (int ns = 0; ns < 4; ++ns) {
      int col = n0 + ns * 16 + (lane & 15);
      bf16x8 b = *(const bf16x8*)(B + (size_t)col * K + k0 + quad * 8);
      acc[ns] = __builtin_amdgcn_mfma_f32_16x16x32_bf16(a, b, acc[ns], 0, 0, 0);
    }
  }
  int h = n0 >> 7;                     // constant over the 64-col tile
  if (DOTS) {
    float av_s[4], av_d[4];
    #pragma unroll
    for (int ns = 0; ns < 4; ++ns) {
      int col = n0 + ns * 16 + (lane & 15);
      av_s[ns] = att_s[col];
      av_d[ns] = att_d[col];
    }
    int H = N >> 7;
    #pragma unroll
    for (int r = 0; r < 4; ++r) {
      float sp = 0.f, dp = 0.f;
      #pragma unroll
      for (int ns = 0; ns < 4; ++ns) {
        sp += acc[ns][r] * av_s[ns];
        dp += acc[ns][r] * av_d[ns];
      }
      #pragma unroll
      for (int w = 1; w < 16; w <<= 1) {   // butterfly within 16-lane quad group
        sp += __shfl_xor(sp, w, 64);
        dp += __shfl_xor(dp, w, 64);
      }
      int orow = m0 + quad * 4 + r;
      if ((lane & 15) == 0 && orow < M) {
        atomicAdd(&a_srcO[(size_t)orow * H + h], sp);
        atomicAdd(&a_dstO[(size_t)orow * H + h], dp);
      }
    }
  }
  #pragma unroll
  for (int ns = 0; ns < 4; ++ns) {
    int col = n0 + ns * 16 + (lane & 15);
    float bv = BIAS ? bias[col] : 0.f;
    #pragma unroll
    for (int r = 0; r < 4; ++r) {
      int orow = m0 + quad * 4 + r;
      if (orow < M) {
        float v = acc[ns][r] + bv;
        if (OUTF32) {
          ((float*)Cv)[(size_t)orow * N + col] = v;
        } else if (HM) {
          ((u16*)Cv)[(size_t)h * ((size_t)NNODES * 128) + (size_t)orow * 128 + (col & 127)] = f2bf(v);
        } else {
          ((u16*)Cv)[(size_t)orow * N + col] = f2bf(v);
        }
      }
    }
  }
}

// ---------------- alpha (softmax weights) per edge, CSR-ordered ----------------
// layer1 (H=8): one wave per dst; lane = i*8+h (i = edge slot group).
// deg<=64 fast path: preload src indices, register-cache e values (8 unrolled slots/lane).
__global__ __launch_bounds__(256) void alpha1_k(const int* __restrict__ offs,
                                                const int* __restrict__ csr_src,
                                                const float* __restrict__ a_src,
                                                const float* __restrict__ a_dst,
                                                float* __restrict__ alpha) {
  int wv = threadIdx.x >> 6;
  int dst = blockIdx.x * 4 + wv;
  if (dst >= NNODES) return;
  int l = threadIdx.x & 63;
  int h = l & 7, i = l >> 3;
  int off = offs[dst];
  int deg = offs[dst + 1] - off;
  const int* srcs = csr_src + off;
  float ad = a_dst[dst * 8 + h];
  float m = -1e30f, ssum = 0.f;
  float* out = alpha + (size_t)h * NETOT + off;
  if (deg <= 64) {
    int sl = srcs[l < deg ? l : deg - 1];       // coalesced preload
    float ev[8];
    #pragma unroll
    for (int t = 0; t < 8; ++t) {
      int jj = i + t * 8;
      float e = -1e30f;
      if (jj < deg) {
        int s = __shfl(sl, jj, 64);
        e = lrelu(a_src[s * 8 + h] + ad);       // 8 h-lanes share s: 32-B segment
      }
      ev[t] = e;
      float nm = fmaxf(m, e);
      ssum = ssum * __expf(m - nm) + ((jj < deg) ? __expf(e - nm) : 0.f);
      m = nm;
    }
    #pragma unroll
    for (int w = 8; w < 64; w <<= 1) {          // reduce over i (lane bits 3..5)
      float om = __shfl_xor(m, w, 64);
      float os = __shfl_xor(ssum, w, 64);
      float nm = fmaxf(m, om);
      ssum = ssum * __expf(m - nm) + os * __expf(om - nm);
      m = nm;
    }
    float inv = 1.f / (ssum + 1e-16f);
    #pragma unroll
    for (int t = 0; t < 8; ++t) {
      int jj = i + t * 8;
      if (jj < deg) out[jj] = __expf(ev[t] - m) * inv;
    }
  } else {
    for (int j = i; j < deg; j += 8) {
      int s = srcs[j];
      float e = lrelu(a_src[s * 8 + h] + ad);
      float nm = fmaxf(m, e);
      ssum = ssum * __expf(m - nm) + __expf(e - nm);
      m = nm;
    }
    #pragma unroll
    for (int w = 8; w < 64; w <<= 1) {
      float om = __shfl_xor(m, w, 64);
      float os = __shfl_xor(ssum, w, 64);
      float nm = fmaxf(m, om);
      ssum = ssum * __expf(m - nm) + os * __expf(om - nm);
      m = nm;
    }
    float inv = 1.f / (ssum + 1e-16f);
    for (int j = i; j < deg; j += 8) {
      int s = srcs[j];
      float e = lrelu(a_src[s * 8 + h] + ad);
      out[j] = __expf(e - m) * inv;
    }
  }
}

// layer2 (H=1): one wave per dst; deg<=64 fast path = one slot per lane.
__global__ __launch_bounds__(256) void alpha2_k(const int* __restrict__ offs,
                                                const int* __restrict__ csr_src,
                                                const float* __restrict__ a_src,
                                                const float* __restrict__ a_dst,
                                                float* __restrict__ alpha) {
  int wv = threadIdx.x >> 6;
  int dst = blockIdx.x * 4 + wv;
  if (dst >= NNODES) return;
  int l = threadIdx.x & 63;
  int off = offs[dst];
  int deg = offs[dst + 1] - off;
  float ad = a_dst[dst];
  if (deg <= 64) {
    float e = -1e30f;
    if (l < deg) e = lrelu(a_src[csr_src[off + l]] + ad);
    float m = e;
    #pragma unroll
    for (int w = 1; w < 64; w <<= 1) m = fmaxf(m, __shfl_xor(m, w, 64));
    float p = (l < deg) ? __expf(e - m) : 0.f;
    float ssum = p;
    #pragma unroll
    for (int w = 1; w < 64; w <<= 1) ssum += __shfl_xor(ssum, w, 64);
    float inv = 1.f / (ssum + 1e-16f);
    if (l < deg) alpha[off + l] = p * inv;
  } else {
    float m = -1e30f, ssum = 0.f;
    for (int j = l; j < deg; j += 64) {
      float e = lrelu(a_src[csr_src[off + j]] + ad);
      float nm = fmaxf(m, e);
      ssum = ssum * __expf(m - nm) + __expf(e - nm);
      m = nm;
    }
    #pragma unroll
    for (int w = 1; w < 64; w <<= 1) {
      float om = __shfl_xor(m, w, 64);
      float os = __shfl_xor(ssum, w, 64);
      float nm = fmaxf(m, om);
      ssum = ssum * __expf(m - nm) + os * __expf(om - nm);
      m = nm;
    }
    float inv = 1.f / (ssum + 1e-16f);
    for (int j = l; j < deg; j += 64) {
      float e = lrelu(a_src[csr_src[off + j]] + ad);
      alpha[off + j] = __expf(e - m) * inv;
    }
  }
}

// ---------------- SpMM layer1 ----------------
// wave per (dst, head); lane = e*16 + c. Edge list preloaded into registers (chunk of 64),
// gather addresses come from __shfl -> all gathers in a chunk are independent (MLP).
// h = blockIdx.x % 8 -> XCD affinity on head slice.
__global__ __launch_bounds__(256) void spmm1(const int* __restrict__ offs,
                                             const int* __restrict__ csr_src,
                                             const float* __restrict__ alpha,
                                             const u16* __restrict__ xp1h,
                                             const float* __restrict__ bias,
                                             u16* __restrict__ out) {
  int lin = blockIdx.x;
  int h = lin & 7;
  int wv = threadIdx.x >> 6;
  int dst = (lin >> 3) * 4 + wv;
  if (dst >= NNODES) return;
  int l = threadIdx.x & 63;
  int e = l >> 4, c = l & 15;
  int off = offs[dst];
  int deg = offs[dst + 1] - off;
  const float* al = alpha + (size_t)h * NETOT + off;
  const int* srcs = csr_src + off;
  const u16* base = xp1h + (size_t)h * ((size_t)NNODES * 128) + c * 8;
  float acc[8] = {0.f, 0.f, 0.f, 0.f, 0.f, 0.f, 0.f, 0.f};
  for (int b0 = 0; b0 < deg; b0 += 64) {
    int cnt = deg - b0; if (cnt > 64) cnt = 64;
    int sl = srcs[b0 + (l < cnt ? l : cnt - 1)];   // coalesced preload
    float wl = (l < cnt) ? al[b0 + l] : 0.f;
    int ng = (cnt + 3) >> 2;
    for (int g = 0; g < ng; ++g) {
      int slot = g * 4 + e;                        // <= 63; padding slots have w=0
      int s = __shfl(sl, slot, 64);
      float w = __shfl(wl, slot, 64);
      bf16x8 f = *(const bf16x8*)(base + (size_t)s * 128);
      #pragma unroll
      for (int k = 0; k < 8; ++k) acc[k] += w * bf2f((u16)f[k]);
    }
  }
  #pragma unroll
  for (int k = 0; k < 8; ++k) {        // reduce over e (lane bits 4,5)
    acc[k] += __shfl_xor(acc[k], 16, 64);
    acc[k] += __shfl_xor(acc[k], 32, 64);
  }
  if (e == 0) {
    int cg = h * 128 + c * 8;
    union { u16 a[8]; uint4 v; } o;
    #pragma unroll
    for (int k = 0; k < 8; ++k) o.a[k] = f2bf(fmaxf(acc[k] + bias[cg + k], 0.f));
    *(uint4*)(out + (size_t)dst * 1024 + cg) = o.v;
  }
}

// ---------------- SpMM layer2 (H=1, C=128) ----------------
__global__ __launch_bounds__(256) void spmm2(const int* __restrict__ offs,
                                             const int* __restrict__ csr_src,
                                             const float* __restrict__ alpha,
                                             const u16* __restrict__ xp2,
                                             const float* __restrict__ bias,
                                             u16* __restrict__ out) {
  int wv = threadIdx.x >> 6;
  int dst = blockIdx.x * 4 + wv;
  if (dst >= NNODES) return;
  int l = threadIdx.x & 63;
  int e = l >> 4, c = l & 15;
  int off = offs[dst];
  int deg = offs[dst + 1] - off;
  const float* al = alpha + off;
  const int* srcs = csr_src + off;
  const u16* base = xp2 + c * 8;
  float acc[8] = {0.f, 0.f, 0.f, 0.f, 0.f, 0.f, 0.f, 0.f};
  for (int b0 = 0; b0 < deg; b0 += 64) {
    int cnt = deg - b0; if (cnt > 64) cnt = 64;
    int sl = srcs[b0 + (l < cnt ? l : cnt - 1)];
    float wl = (l < cnt) ? al[b0 + l] : 0.f;
    int ng = (cnt + 3) >> 2;
    for (int g = 0; g < ng; ++g) {
      int slot = g * 4 + e;
      int s = __shfl(sl, slot, 64);
      float w = __shfl(wl, slot, 64);
      bf16x8 f = *(const bf16x8*)(base + (size_t)s * 128);
      #pragma unroll
      for (int k = 0; k < 8; ++k) acc[k] += w * bf2f((u16)f[k]);
    }
  }
  #pragma unroll
  for (int k = 0; k < 8; ++k) {
    acc[k] += __shfl_xor(acc[k], 16, 64);
    acc[k] += __shfl_xor(acc[k], 32, 64);
  }
  if (e == 0) {
    int cg = c * 8;
    union { u16 a[8]; uint4 v; } o;
    #pragma unroll
    for (int k = 0; k < 8; ++k) o.a[k] = f2bf(fmaxf(acc[k] + bias[cg + k], 0.f));
    *(uint4*)(out + (size_t)dst * 128 + cg) = o.v;
  }
}

// ---------------- launch ----------------
extern "C" void kernel_launch(void* const* d_in, const int* in_sizes, int n_in,
                              void* d_out, int out_size, void* d_ws, size_t ws_size,
                              hipStream_t stream) {
  const float* cons    = (const float*)d_in[0];
  const float* cols    = (const float*)d_in[1];
  const float* node_W  = (const float*)d_in[2];
  const float* node_b  = (const float*)d_in[3];
  const float* col_W   = (const float*)d_in[4];
  const float* col_b   = (const float*)d_in[5];
  const float* W1      = (const float*)d_in[6];
  const float* att_s1  = (const float*)d_in[7];
  const float* att_d1  = (const float*)d_in[8];
  const float* b1      = (const float*)d_in[9];
  const float* W2      = (const float*)d_in[10];
  const float* att_s2  = (const float*)d_in[11];
  const float* att_d2  = (const float*)d_in[12];
  const float* b2      = (const float*)d_in[13];
  const float* out_W   = (const float*)d_in[14];
  const float* out_b   = (const float*)d_in[15];
  const int* edges     = (const int*)d_in[16];

  char* p = (char*)d_ws;
  auto alloc = [&](size_t bytes) {
    char* r = p;
    p += (bytes + 255) & ~(size_t)255;
    return r;
  };
  u16* emb0    = (u16*)alloc((size_t)NNODES * 128 * 2);        // bf16
  u16* xp1h    = (u16*)alloc((size_t)8 * NNODES * 128 * 2);    // bf16, head-major
  u16* emb2    = (u16*)alloc((size_t)NNODES * 1024 * 2);       // bf16
  u16* xp2     = (u16*)alloc((size_t)NNODES * 128 * 2);        // bf16
  u16* emb3    = (u16*)alloc((size_t)NNODES * 128 * 2);        // bf16
  u16* Wbf     = (u16*)alloc((size_t)(W1N + W2N + OWN) * 2);   // W1|W2|out_W contiguous
  // ---- contiguous zero region: as1, ad1, as2, ad2, counts ----
  float* as1   = (float*)alloc((size_t)NNODES * 8 * 4);        // 640000 B (256-mult)
  float* ad1   = (float*)alloc((size_t)NNODES * 8 * 4);        // 640000 B
  float* as2   = (float*)alloc((size_t)NNODES * 4);            // pads to 80128 B
  float* ad2   = (float*)alloc((size_t)NNODES * 4);            // pads to 80128 B
  int* counts  = (int*)alloc((size_t)NNODES * 4);              // pads to 80128 B
  size_t zspan = (char*)(counts + NNODES) - (char*)as1;
  // ---- end zero region ----
  float* alp1  = (float*)alloc((size_t)8 * NETOT * 4);         // head-major [8][NETOT]
  float* alp2  = (float*)alloc((size_t)NETOT * 4);
  int* offs    = (int*)alloc((size_t)(NNODES + 1) * 4);
  int* cursor  = (int*)alloc((size_t)NNODES * 4);
  int* csrsrc  = (int*)alloc((size_t)NETOT * 4);
  int* lscan   = (int*)alloc((size_t)NSCANB * 256 * 4);
  int* bsum    = (int*)alloc((size_t)NSCANB * 4);
  int* bbase   = (int*)alloc((size_t)NSCANB * 4);

  u16* W1bf = Wbf;
  u16* W2bf = Wbf + W1N;
  u16* oWbf = Wbf + W1N + W2N;

  hipMemsetAsync(as1, 0, zspan, stream);

  // CSR build
  count_edges<<<(NETOT + 255) / 256, 256, 0, stream>>>(edges, counts);
  scan_a<<<NSCANB, 256, 0, stream>>>(counts, lscan, bsum);
  scan_b<<<1, 128, 0, stream>>>(bsum, bbase);
  scan_c<<<NSCANB, 256, 0, stream>>>(lscan, counts, bbase, offs, cursor);
  fill_edges<<<(NETOT + 255) / 256, 256, 0, stream>>>(edges, cursor, csrsrc);

  // weight conversions f32 -> bf16 (fused)
  cvt_all<<<(W1N + W2N + OWN + 255) / 256, 256, 0, stream>>>(W1, W2, out_W, Wbf);

  // layer 0 embed
  embed0<<<(NNODES * 128 + 255) / 256, 256, 0, stream>>>(cons, cols, node_W, node_b,
                                                         col_W, col_b, emb0);

  // GAT layer 1: GEMM (fused dots, head-major out) -> alpha -> SpMM
  gemm_bt<true, true, false, false><<<dim3((NNODES + 63) / 64, 1024 / 64), 256, 0, stream>>>(
      emb0, W1bf, nullptr, xp1h, att_s1, att_d1, as1, ad1, NNODES, 1024, 128);
  alpha1_k<<<(NNODES + 3) / 4, 256, 0, stream>>>(offs, csrsrc, as1, ad1, alp1);
  spmm1<<<8 * ((NNODES + 3) / 4), 256, 0, stream>>>(offs, csrsrc, alp1, xp1h, b1, emb2);

  // GAT layer 2: GEMM (fused dots) -> alpha -> SpMM
  gemm_bt<true, false, false, false><<<dim3((NNODES + 63) / 64, 128 / 64), 256, 0, stream>>>(
      emb2, W2bf, nullptr, xp2, att_s2, att_d2, as2, ad2, NNODES, 128, 1024);
  alpha2_k<<<(NNODES + 3) / 4, 256, 0, stream>>>(offs, csrsrc, as2, ad2, alp2);
  spmm2<<<(NNODES + 3) / 4, 256, 0, stream>>>(offs, csrsrc, alp2, xp2, b2, emb3);

  // output projection: rows 10000..19999, f32 out with bias
  gemm_bt<false, false, true, true><<<dim3((NCOLSN + 63) / 64, 128 / 64), 256, 0, stream>>>(
      emb3 + (size_t)NCONS * 128, oWbf, out_b, d_out, nullptr, nullptr, nullptr, nullptr,
      NCOLSN, 128, 128);
}

// Round 6
// 325.328 us; speedup vs baseline: 1.4615x; 1.1309x over previous
//
#include <hip/hip_runtime.h>

// ---------------- problem constants ----------------
#define NCONS 10000
#define NCOLSN 10000
#define NNODES 20000         // NCONS + NCOLSN
#define NEDGE 200000
#define NETOT 220000         // NEDGE + NNODES self loops
#define NEG_SLOPE 0.2f
#define NSCANB 79            // ceil(NNODES/256)

typedef unsigned short u16;
typedef __attribute__((ext_vector_type(8))) short bf16x8;
typedef __attribute__((ext_vector_type(4))) float f32x4;

__device__ __forceinline__ float bf2f(u16 u) {
  return __uint_as_float(((unsigned int)u) << 16);
}
__device__ __forceinline__ u16 f2bf(float f) {
  unsigned int x = __float_as_uint(f);
  return (u16)((x + 0x7fffu + ((x >> 16) & 1u)) >> 16);
}
__device__ __forceinline__ float lrelu(float v) {
  return v >= 0.f ? v : NEG_SLOPE * v;
}
// async global->LDS, 16 B per lane; LDS dest must be wave-uniform base + lane*16
__device__ __forceinline__ void gl2lds16(const u16* g, u16* l) {
  __builtin_amdgcn_global_load_lds(
      (const __attribute__((address_space(1))) unsigned int*)g,
      (__attribute__((address_space(3))) unsigned int*)l, 16, 0, 0);
}

// ---------------- fused weight conversion f32->bf16 (W1|W2|out_W into contiguous dst) --------
#define W1N (1024 * 128)
#define W2N (128 * 1024)
#define OWN (128 * 128)
__global__ void cvt_all(const float* __restrict__ W1, const float* __restrict__ W2,
                        const float* __restrict__ oW, u16* __restrict__ out) {
  int i = blockIdx.x * 256 + threadIdx.x;
  if (i >= W1N + W2N + OWN) return;
  float v;
  if (i < W1N) v = W1[i];
  else if (i < W1N + W2N) v = W2[i - W1N];
  else v = oW[i - W1N - W2N];
  out[i] = f2bf(v);
}

// ---------------- CSR build ----------------
__global__ void count_edges(const int* __restrict__ edges, int* __restrict__ counts) {
  int i = blockIdx.x * 256 + threadIdx.x;
  if (i >= NETOT) return;
  int dst = (i < NEDGE) ? edges[NEDGE + i] : (i - NEDGE);
  atomicAdd(&counts[dst], 1);
}

__global__ void scan_a(const int* __restrict__ counts, int* __restrict__ lscan,
                       int* __restrict__ bsum) {
  __shared__ int sh[256];
  int t = threadIdx.x;
  int i = blockIdx.x * 256 + t;
  int v = (i < NNODES) ? counts[i] : 0;
  sh[t] = v;
  __syncthreads();
  for (int d = 1; d < 256; d <<= 1) {
    int add = (t >= d) ? sh[t - d] : 0;
    __syncthreads();
    sh[t] += add;
    __syncthreads();
  }
  lscan[i] = sh[t];
  if (t == 255) bsum[blockIdx.x] = sh[255];
}
__global__ void scan_b(const int* __restrict__ bsum, int* __restrict__ bbase) {
  __shared__ int sh[128];
  int t = threadIdx.x;
  int v = (t < NSCANB) ? bsum[t] : 0;
  sh[t] = v;
  __syncthreads();
  for (int d = 1; d < 128; d <<= 1) {
    int add = (t >= d) ? sh[t - d] : 0;
    __syncthreads();
    sh[t] += add;
    __syncthreads();
  }
  if (t < NSCANB) bbase[t] = sh[t] - v;
}
__global__ void scan_c(const int* __restrict__ lscan, const int* __restrict__ counts,
                       const int* __restrict__ bbase, int* __restrict__ offsets,
                       int* __restrict__ cursor) {
  int t = threadIdx.x;
  int i = blockIdx.x * 256 + t;
  if (i == 0) offsets[0] = 0;
  if (i < NNODES) {
    int incl = lscan[i] + bbase[blockIdx.x];
    offsets[i + 1] = incl;
    cursor[i] = incl - counts[i];
  }
}

__global__ void fill_edges(const int* __restrict__ edges, int* __restrict__ cursor,
                           int* __restrict__ csr_src) {
  int i = blockIdx.x * 256 + threadIdx.x;
  if (i >= NETOT) return;
  int src, dst;
  if (i < NEDGE) { src = edges[i]; dst = edges[NEDGE + i]; }
  else { src = dst = i - NEDGE; }
  int pos = atomicAdd(&cursor[dst], 1);
  csr_src[pos] = src;
}

// ---------------- layer 0 embed (tile(x,(1,2)) folded), f32 in -> bf16 out ----------------
__global__ void embed0(const float* __restrict__ cons, const float* __restrict__ cols,
                       const float* __restrict__ nW, const float* __restrict__ nb,
                       const float* __restrict__ cW, const float* __restrict__ cb,
                       u16* __restrict__ emb) {
  int idx = blockIdx.x * 256 + threadIdx.x;
  if (idx >= NNODES * 128) return;
  int row = idx >> 7, o = idx & 127;
  float acc;
  if (row < NCONS) {
    acc = nb[o];
    #pragma unroll
    for (int k = 0; k < 4; ++k)
      acc += cons[row * 4 + k] * (nW[o * 8 + k] + nW[o * 8 + 4 + k]);
  } else {
    int r = row - NCONS;
    acc = cb[o];
    #pragma unroll
    for (int k = 0; k < 8; ++k)
      acc += cols[r * 8 + k] * (cW[o * 16 + k] + cW[o * 16 + 8 + k]);
  }
  emb[idx] = f2bf(fmaxf(acc, 0.f));
}

// ---------------- LDS-staged GEMM (m97 structure): C[M,N] = A[M,K] @ B[N,K]^T ----------------
// 128x128 block tile, BK=32, 256 thr = 4 waves, each wave 64x64 (4x4 MFMA 16x16x32).
// DOTS: fused attention-dot partials -> atomicAdd a_src/a_dst [M, N/128] (h = blockIdx.y)
// HM:   head-major store C[(col>>7)][row][col&127]
template <bool DOTS, bool HM, bool BIAS, bool OUTF32>
__global__ __launch_bounds__(256) void gemm_bt(const u16* __restrict__ A, const u16* __restrict__ B,
                                               const float* __restrict__ bias, void* __restrict__ Cv,
                                               const float* __restrict__ att_s,
                                               const float* __restrict__ att_d,
                                               float* __restrict__ a_srcO, float* __restrict__ a_dstO,
                                               int M, int N, int K) {
  __shared__ u16 sA[128 * 32];
  __shared__ u16 sB[128 * 32];
  int tid = threadIdx.x;
  int wv = tid >> 6;
  int lane = tid & 63;
  int quad = lane >> 4;
  int l16 = lane & 15;
  int m0 = blockIdx.x * 128;
  int n0g = blockIdx.y * 128;
  int rm = (wv >> 1) * 64;             // wave row base in tile
  int cn = (wv & 1) * 64;              // wave col base in tile

  f32x4 acc[4][4];
  #pragma unroll
  for (int mi = 0; mi < 4; ++mi)
    #pragma unroll
    for (int ni = 0; ni < 4; ++ni) acc[mi][ni] = f32x4{0.f, 0.f, 0.f, 0.f};

  for (int k0 = 0; k0 < K; k0 += 32) {
    // stage A,B tiles (128 rows x 32 cols bf16 = 8192 B each; 2 chunks of 1024 B per wave)
    #pragma unroll
    for (int q = 0; q < 2; ++q) {
      int off = (q * 4 + wv) * 1024 + lane * 16;   // byte offset in tile
      int row = off >> 6;                           // 64 B per row
      int kk = (off & 63) >> 1;                     // u16 col within row
      int rg = m0 + row; if (rg >= M) rg = M - 1;
      gl2lds16(A + (size_t)rg * K + k0 + kk, &sA[off >> 1]);
      gl2lds16(B + (size_t)(n0g + row) * K + k0 + kk, &sB[off >> 1]);
    }
    __syncthreads();
    bf16x8 af[4], bf[4];
    #pragma unroll
    for (int mi = 0; mi < 4; ++mi)
      af[mi] = *(const bf16x8*)&sA[(rm + mi * 16 + l16) * 32 + quad * 8];
    #pragma unroll
    for (int ni = 0; ni < 4; ++ni)
      bf[ni] = *(const bf16x8*)&sB[(cn + ni * 16 + l16) * 32 + quad * 8];
    #pragma unroll
    for (int mi = 0; mi < 4; ++mi)
      #pragma unroll
      for (int ni = 0; ni < 4; ++ni)
        acc[mi][ni] = __builtin_amdgcn_mfma_f32_16x16x32_bf16(af[mi], bf[ni], acc[mi][ni], 0, 0, 0);
    __syncthreads();
  }

  int h = n0g >> 7;                    // one head per 128-col block
  if (DOTS) {
    float av_s[4], av_d[4];
    #pragma unroll
    for (int ni = 0; ni < 4; ++ni) {
      int col = n0g + cn + ni * 16 + l16;
      av_s[ni] = att_s[col];
      av_d[ni] = att_d[col];
    }
    int H = N >> 7;
    #pragma unroll
    for (int mi = 0; mi < 4; ++mi) {
      #pragma unroll
      for (int r = 0; r < 4; ++r) {
        float sp = 0.f, dp = 0.f;
        #pragma unroll
        for (int ni = 0; ni < 4; ++ni) {
          sp += acc[mi][ni][r] * av_s[ni];
          dp += acc[mi][ni][r] * av_d[ni];
        }
        #pragma unroll
        for (int w = 1; w < 16; w <<= 1) {   // reduce over the 16 col-lanes
          sp += __shfl_xor(sp, w, 64);
          dp += __shfl_xor(dp, w, 64);
        }
        int orow = m0 + rm + mi * 16 + quad * 4 + r;
        if (l16 == 0 && orow < M) {
          atomicAdd(&a_srcO[(size_t)orow * H + h], sp);
          atomicAdd(&a_dstO[(size_t)orow * H + h], dp);
        }
      }
    }
  }
  #pragma unroll
  for (int ni = 0; ni < 4; ++ni) {
    int col = n0g + cn + ni * 16 + l16;
    float bv = BIAS ? bias[col] : 0.f;
    #pragma unroll
    for (int mi = 0; mi < 4; ++mi) {
      #pragma unroll
      for (int r = 0; r < 4; ++r) {
        int orow = m0 + rm + mi * 16 + quad * 4 + r;
        if (orow < M) {
          float v = acc[mi][ni][r] + bv;
          if (OUTF32) {
            ((float*)Cv)[(size_t)orow * N + col] = v;
          } else if (HM) {
            ((u16*)Cv)[(size_t)h * ((size_t)NNODES * 128) + (size_t)orow * 128 + (col & 127)] = f2bf(v);
          } else {
            ((u16*)Cv)[(size_t)orow * N + col] = f2bf(v);
          }
        }
      }
    }
  }
}

// ---------------- alpha (softmax weights) per edge, CSR-ordered ----------------
// layer1 (H=8): one wave per dst; lane = i*8+h (i = edge slot group).
// deg<=64 fast path: preload src indices, register-cache e values (8 unrolled slots/lane).
__global__ __launch_bounds__(256) void alpha1_k(const int* __restrict__ offs,
                                                const int* __restrict__ csr_src,
                                                const float* __restrict__ a_src,
                                                const float* __restrict__ a_dst,
                                                float* __restrict__ alpha) {
  int wv = threadIdx.x >> 6;
  int dst = blockIdx.x * 4 + wv;
  if (dst >= NNODES) return;
  int l = threadIdx.x & 63;
  int h = l & 7, i = l >> 3;
  int off = offs[dst];
  int deg = offs[dst + 1] - off;
  const int* srcs = csr_src + off;
  float ad = a_dst[dst * 8 + h];
  float m = -1e30f, ssum = 0.f;
  float* out = alpha + (size_t)h * NETOT + off;
  if (deg <= 64) {
    int sl = srcs[l < deg ? l : deg - 1];       // coalesced preload
    float ev[8];
    #pragma unroll
    for (int t = 0; t < 8; ++t) {
      int jj = i + t * 8;
      float e = -1e30f;
      if (jj < deg) {
        int s = __shfl(sl, jj, 64);
        e = lrelu(a_src[s * 8 + h] + ad);       // 8 h-lanes share s: 32-B segment
      }
      ev[t] = e;
      float nm = fmaxf(m, e);
      ssum = ssum * __expf(m - nm) + ((jj < deg) ? __expf(e - nm) : 0.f);
      m = nm;
    }
    #pragma unroll
    for (int w = 8; w < 64; w <<= 1) {          // reduce over i (lane bits 3..5)
      float om = __shfl_xor(m, w, 64);
      float os = __shfl_xor(ssum, w, 64);
      float nm = fmaxf(m, om);
      ssum = ssum * __expf(m - nm) + os * __expf(om - nm);
      m = nm;
    }
    float inv = 1.f / (ssum + 1e-16f);
    #pragma unroll
    for (int t = 0; t < 8; ++t) {
      int jj = i + t * 8;
      if (jj < deg) out[jj] = __expf(ev[t] - m) * inv;
    }
  } else {
    for (int j = i; j < deg; j += 8) {
      int s = srcs[j];
      float e = lrelu(a_src[s * 8 + h] + ad);
      float nm = fmaxf(m, e);
      ssum = ssum * __expf(m - nm) + __expf(e - nm);
      m = nm;
    }
    #pragma unroll
    for (int w = 8; w < 64; w <<= 1) {
      float om = __shfl_xor(m, w, 64);
      float os = __shfl_xor(ssum, w, 64);
      float nm = fmaxf(m, om);
      ssum = ssum * __expf(m - nm) + os * __expf(om - nm);
      m = nm;
    }
    float inv = 1.f / (ssum + 1e-16f);
    for (int j = i; j < deg; j += 8) {
      int s = srcs[j];
      float e = lrelu(a_src[s * 8 + h] + ad);
      out[j] = __expf(e - m) * inv;
    }
  }
}

// layer2 (H=1): one wave per dst; deg<=64 fast path = one slot per lane.
__global__ __launch_bounds__(256) void alpha2_k(const int* __restrict__ offs,
                                                const int* __restrict__ csr_src,
                                                const float* __restrict__ a_src,
                                                const float* __restrict__ a_dst,
                                                float* __restrict__ alpha) {
  int wv = threadIdx.x >> 6;
  int dst = blockIdx.x * 4 + wv;
  if (dst >= NNODES) return;
  int l = threadIdx.x & 63;
  int off = offs[dst];
  int deg = offs[dst + 1] - off;
  float ad = a_dst[dst];
  if (deg <= 64) {
    float e = -1e30f;
    if (l < deg) e = lrelu(a_src[csr_src[off + l]] + ad);
    float m = e;
    #pragma unroll
    for (int w = 1; w < 64; w <<= 1) m = fmaxf(m, __shfl_xor(m, w, 64));
    float p = (l < deg) ? __expf(e - m) : 0.f;
    float ssum = p;
    #pragma unroll
    for (int w = 1; w < 64; w <<= 1) ssum += __shfl_xor(ssum, w, 64);
    float inv = 1.f / (ssum + 1e-16f);
    if (l < deg) alpha[off + l] = p * inv;
  } else {
    float m = -1e30f, ssum = 0.f;
    for (int j = l; j < deg; j += 64) {
      float e = lrelu(a_src[csr_src[off + j]] + ad);
      float nm = fmaxf(m, e);
      ssum = ssum * __expf(m - nm) + __expf(e - nm);
      m = nm;
    }
    #pragma unroll
    for (int w = 1; w < 64; w <<= 1) {
      float om = __shfl_xor(m, w, 64);
      float os = __shfl_xor(ssum, w, 64);
      float nm = fmaxf(m, om);
      ssum = ssum * __expf(m - nm) + os * __expf(om - nm);
      m = nm;
    }
    float inv = 1.f / (ssum + 1e-16f);
    for (int j = l; j < deg; j += 64) {
      float e = lrelu(a_src[csr_src[off + j]] + ad);
      alpha[off + j] = __expf(e - m) * inv;
    }
  }
}

// ---------------- SpMM layer1 ----------------
// wave per (dst, head); lane = e*16 + c. Edge list preloaded into registers (chunk of 64),
// gather addresses come from __shfl -> all gathers in a chunk are independent (MLP).
// h = blockIdx.x % 8 -> XCD affinity on head slice.
__global__ __launch_bounds__(256) void spmm1(const int* __restrict__ offs,
                                             const int* __restrict__ csr_src,
                                             const float* __restrict__ alpha,
                                             const u16* __restrict__ xp1h,
                                             const float* __restrict__ bias,
                                             u16* __restrict__ out) {
  int lin = blockIdx.x;
  int h = lin & 7;
  int wv = threadIdx.x >> 6;
  int dst = (lin >> 3) * 4 + wv;
  if (dst >= NNODES) return;
  int l = threadIdx.x & 63;
  int e = l >> 4, c = l & 15;
  int off = offs[dst];
  int deg = offs[dst + 1] - off;
  const float* al = alpha + (size_t)h * NETOT + off;
  const int* srcs = csr_src + off;
  const u16* base = xp1h + (size_t)h * ((size_t)NNODES * 128) + c * 8;
  float acc[8] = {0.f, 0.f, 0.f, 0.f, 0.f, 0.f, 0.f, 0.f};
  for (int b0 = 0; b0 < deg; b0 += 64) {
    int cnt = deg - b0; if (cnt > 64) cnt = 64;
    int sl = srcs[b0 + (l < cnt ? l : cnt - 1)];   // coalesced preload
    float wl = (l < cnt) ? al[b0 + l] : 0.f;
    int ng = (cnt + 3) >> 2;
    for (int g = 0; g < ng; ++g) {
      int slot = g * 4 + e;                        // <= 63; padding slots have w=0
      int s = __shfl(sl, slot, 64);
      float w = __shfl(wl, slot, 64);
      bf16x8 f = *(const bf16x8*)(base + (size_t)s * 128);
      #pragma unroll
      for (int k = 0; k < 8; ++k) acc[k] += w * bf2f((u16)f[k]);
    }
  }
  #pragma unroll
  for (int k = 0; k < 8; ++k) {        // reduce over e (lane bits 4,5)
    acc[k] += __shfl_xor(acc[k], 16, 64);
    acc[k] += __shfl_xor(acc[k], 32, 64);
  }
  if (e == 0) {
    int cg = h * 128 + c * 8;
    union { u16 a[8]; uint4 v; } o;
    #pragma unroll
    for (int k = 0; k < 8; ++k) o.a[k] = f2bf(fmaxf(acc[k] + bias[cg + k], 0.f));
    *(uint4*)(out + (size_t)dst * 1024 + cg) = o.v;
  }
}

// ---------------- SpMM layer2 (H=1, C=128) ----------------
__global__ __launch_bounds__(256) void spmm2(const int* __restrict__ offs,
                                             const int* __restrict__ csr_src,
                                             const float* __restrict__ alpha,
                                             const u16* __restrict__ xp2,
                                             const float* __restrict__ bias,
                                             u16* __restrict__ out) {
  int wv = threadIdx.x >> 6;
  int dst = blockIdx.x * 4 + wv;
  if (dst >= NNODES) return;
  int l = threadIdx.x & 63;
  int e = l >> 4, c = l & 15;
  int off = offs[dst];
  int deg = offs[dst + 1] - off;
  const float* al = alpha + off;
  const int* srcs = csr_src + off;
  const u16* base = xp2 + c * 8;
  float acc[8] = {0.f, 0.f, 0.f, 0.f, 0.f, 0.f, 0.f, 0.f};
  for (int b0 = 0; b0 < deg; b0 += 64) {
    int cnt = deg - b0; if (cnt > 64) cnt = 64;
    int sl = srcs[b0 + (l < cnt ? l : cnt - 1)];
    float wl = (l < cnt) ? al[b0 + l] : 0.f;
    int ng = (cnt + 3) >> 2;
    for (int g = 0; g < ng; ++g) {
      int slot = g * 4 + e;
      int s = __shfl(sl, slot, 64);
      float w = __shfl(wl, slot, 64);
      bf16x8 f = *(const bf16x8*)(base + (size_t)s * 128);
      #pragma unroll
      for (int k = 0; k < 8; ++k) acc[k] += w * bf2f((u16)f[k]);
    }
  }
  #pragma unroll
  for (int k = 0; k < 8; ++k) {
    acc[k] += __shfl_xor(acc[k], 16, 64);
    acc[k] += __shfl_xor(acc[k], 32, 64);
  }
  if (e == 0) {
    int cg = c * 8;
    union { u16 a[8]; uint4 v; } o;
    #pragma unroll
    for (int k = 0; k < 8; ++k) o.a[k] = f2bf(fmaxf(acc[k] + bias[cg + k], 0.f));
    *(uint4*)(out + (size_t)dst * 128 + cg) = o.v;
  }
}

// ---------------- launch ----------------
extern "C" void kernel_launch(void* const* d_in, const int* in_sizes, int n_in,
                              void* d_out, int out_size, void* d_ws, size_t ws_size,
                              hipStream_t stream) {
  const float* cons    = (const float*)d_in[0];
  const float* cols    = (const float*)d_in[1];
  const float* node_W  = (const float*)d_in[2];
  const float* node_b  = (const float*)d_in[3];
  const float* col_W   = (const float*)d_in[4];
  const float* col_b   = (const float*)d_in[5];
  const float* W1      = (const float*)d_in[6];
  const float* att_s1  = (const float*)d_in[7];
  const float* att_d1  = (const float*)d_in[8];
  const float* b1      = (const float*)d_in[9];
  const float* W2      = (const float*)d_in[10];
  const float* att_s2  = (const float*)d_in[11];
  const float* att_d2  = (const float*)d_in[12];
  const float* b2      = (const float*)d_in[13];
  const float* out_W   = (const float*)d_in[14];
  const float* out_b   = (const float*)d_in[15];
  const int* edges     = (const int*)d_in[16];

  char* p = (char*)d_ws;
  auto alloc = [&](size_t bytes) {
    char* r = p;
    p += (bytes + 255) & ~(size_t)255;
    return r;
  };
  u16* emb0    = (u16*)alloc((size_t)NNODES * 128 * 2);        // bf16
  u16* xp1h    = (u16*)alloc((size_t)8 * NNODES * 128 * 2);    // bf16, head-major
  u16* emb2    = (u16*)alloc((size_t)NNODES * 1024 * 2);       // bf16
  u16* xp2     = (u16*)alloc((size_t)NNODES * 128 * 2);        // bf16
  u16* emb3    = (u16*)alloc((size_t)NNODES * 128 * 2);        // bf16
  u16* Wbf     = (u16*)alloc((size_t)(W1N + W2N + OWN) * 2);   // W1|W2|out_W contiguous
  // ---- contiguous zero region: as1, ad1, as2, ad2, counts ----
  float* as1   = (float*)alloc((size_t)NNODES * 8 * 4);        // 640000 B (256-mult)
  float* ad1   = (float*)alloc((size_t)NNODES * 8 * 4);        // 640000 B
  float* as2   = (float*)alloc((size_t)NNODES * 4);            // pads to 80128 B
  float* ad2   = (float*)alloc((size_t)NNODES * 4);            // pads to 80128 B
  int* counts  = (int*)alloc((size_t)NNODES * 4);              // pads to 80128 B
  size_t zspan = (char*)(counts + NNODES) - (char*)as1;
  // ---- end zero region ----
  float* alp1  = (float*)alloc((size_t)8 * NETOT * 4);         // head-major [8][NETOT]
  float* alp2  = (float*)alloc((size_t)NETOT * 4);
  int* offs    = (int*)alloc((size_t)(NNODES + 1) * 4);
  int* cursor  = (int*)alloc((size_t)NNODES * 4);
  int* csrsrc  = (int*)alloc((size_t)NETOT * 4);
  int* lscan   = (int*)alloc((size_t)NSCANB * 256 * 4);
  int* bsum    = (int*)alloc((size_t)NSCANB * 4);
  int* bbase   = (int*)alloc((size_t)NSCANB * 4);

  u16* W1bf = Wbf;
  u16* W2bf = Wbf + W1N;
  u16* oWbf = Wbf + W1N + W2N;

  hipMemsetAsync(as1, 0, zspan, stream);

  // CSR build
  count_edges<<<(NETOT + 255) / 256, 256, 0, stream>>>(edges, counts);
  scan_a<<<NSCANB, 256, 0, stream>>>(counts, lscan, bsum);
  scan_b<<<1, 128, 0, stream>>>(bsum, bbase);
  scan_c<<<NSCANB, 256, 0, stream>>>(lscan, counts, bbase, offs, cursor);
  fill_edges<<<(NETOT + 255) / 256, 256, 0, stream>>>(edges, cursor, csrsrc);

  // weight conversions f32 -> bf16 (fused)
  cvt_all<<<(W1N + W2N + OWN + 255) / 256, 256, 0, stream>>>(W1, W2, out_W, Wbf);

  // layer 0 embed
  embed0<<<(NNODES * 128 + 255) / 256, 256, 0, stream>>>(cons, cols, node_W, node_b,
                                                         col_W, col_b, emb0);

  // GAT layer 1: GEMM (fused dots, head-major out) -> alpha -> SpMM
  gemm_bt<true, true, false, false><<<dim3((NNODES + 127) / 128, 1024 / 128), 256, 0, stream>>>(
      emb0, W1bf, nullptr, xp1h, att_s1, att_d1, as1, ad1, NNODES, 1024, 128);
  alpha1_k<<<(NNODES + 3) / 4, 256, 0, stream>>>(offs, csrsrc, as1, ad1, alp1);
  spmm1<<<8 * ((NNODES + 3) / 4), 256, 0, stream>>>(offs, csrsrc, alp1, xp1h, b1, emb2);

  // GAT layer 2: GEMM (fused dots) -> alpha -> SpMM
  gemm_bt<true, false, false, false><<<dim3((NNODES + 127) / 128, 1), 256, 0, stream>>>(
      emb2, W2bf, nullptr, xp2, att_s2, att_d2, as2, ad2, NNODES, 128, 1024);
  alpha2_k<<<(NNODES + 3) / 4, 256, 0, stream>>>(offs, csrsrc, as2, ad2, alp2);
  spmm2<<<(NNODES + 3) / 4, 256, 0, stream>>>(offs, csrsrc, alp2, xp2, b2, emb3);

  // output projection: rows 10000..19999, f32 out with bias
  gemm_bt<false, false, true, true><<<dim3((NCOLSN + 127) / 128, 1), 256, 0, stream>>>(
      emb3 + (size_t)NCONS * 128, oWbf, out_b, d_out, nullptr, nullptr, nullptr, nullptr,
      NCOLSN, 128, 128);
}

// Round 7
// 322.478 us; speedup vs baseline: 1.4744x; 1.0088x over previous
//
#include <hip/hip_runtime.h>

// ---------------- problem constants ----------------
#define NCONS 10000
#define NCOLSN 10000
#define NNODES 20000         // NCONS + NCOLSN
#define NEDGE 200000
#define NETOT 220000         // NEDGE + NNODES self loops
#define NEG_SLOPE 0.2f
#define NSCANB 79            // ceil(NNODES/256)

typedef unsigned short u16;
typedef __attribute__((ext_vector_type(8))) short bf16x8;
typedef __attribute__((ext_vector_type(4))) float f32x4;

__device__ __forceinline__ float bf2f(u16 u) {
  return __uint_as_float(((unsigned int)u) << 16);
}
__device__ __forceinline__ u16 f2bf(float f) {
  unsigned int x = __float_as_uint(f);
  return (u16)((x + 0x7fffu + ((x >> 16) & 1u)) >> 16);
}
__device__ __forceinline__ float lrelu(float v) {
  return v >= 0.f ? v : NEG_SLOPE * v;
}
// async global->LDS, 16 B per lane; LDS dest must be wave-uniform base + lane*16
__device__ __forceinline__ void gl2lds16(const u16* g, u16* l) {
  __builtin_amdgcn_global_load_lds(
      (const __attribute__((address_space(1))) unsigned int*)g,
      (__attribute__((address_space(3))) unsigned int*)l, 16, 0, 0);
}

#define W1N (1024 * 128)
#define W2N (128 * 1024)
#define OWN (128 * 128)
#define EMB0N (NNODES * 128)

// ---------------- fused: layer-0 embed + weight f32->bf16 conversion ----------------
__global__ void prep(const float* __restrict__ cons, const float* __restrict__ cols,
                     const float* __restrict__ nW, const float* __restrict__ nb,
                     const float* __restrict__ cW, const float* __restrict__ cb,
                     const float* __restrict__ W1, const float* __restrict__ W2,
                     const float* __restrict__ oW, u16* __restrict__ emb,
                     u16* __restrict__ Wbf) {
  int idx = blockIdx.x * 256 + threadIdx.x;
  if (idx < EMB0N) {
    int row = idx >> 7, o = idx & 127;
    float acc;
    if (row < NCONS) {
      acc = nb[o];
      #pragma unroll
      for (int k = 0; k < 4; ++k)
        acc += cons[row * 4 + k] * (nW[o * 8 + k] + nW[o * 8 + 4 + k]);
    } else {
      int r = row - NCONS;
      acc = cb[o];
      #pragma unroll
      for (int k = 0; k < 8; ++k)
        acc += cols[r * 8 + k] * (cW[o * 16 + k] + cW[o * 16 + 8 + k]);
    }
    emb[idx] = f2bf(fmaxf(acc, 0.f));
  } else {
    int i = idx - EMB0N;
    if (i >= W1N + W2N + OWN) return;
    float v;
    if (i < W1N) v = W1[i];
    else if (i < W1N + W2N) v = W2[i - W1N];
    else v = oW[i - W1N - W2N];
    Wbf[i] = f2bf(v);
  }
}

// ---------------- CSR build ----------------
__global__ void count_edges(const int* __restrict__ edges, int* __restrict__ counts) {
  int i = blockIdx.x * 256 + threadIdx.x;
  if (i >= NETOT) return;
  int dst = (i < NEDGE) ? edges[NEDGE + i] : (i - NEDGE);
  atomicAdd(&counts[dst], 1);
}

__global__ void scan_a(const int* __restrict__ counts, int* __restrict__ lscan,
                       int* __restrict__ bsum) {
  __shared__ int sh[256];
  int t = threadIdx.x;
  int i = blockIdx.x * 256 + t;
  int v = (i < NNODES) ? counts[i] : 0;
  sh[t] = v;
  __syncthreads();
  for (int d = 1; d < 256; d <<= 1) {
    int add = (t >= d) ? sh[t - d] : 0;
    __syncthreads();
    sh[t] += add;
    __syncthreads();
  }
  lscan[i] = sh[t];
  if (t == 255) bsum[blockIdx.x] = sh[255];
}
__global__ void scan_b(const int* __restrict__ bsum, int* __restrict__ bbase) {
  __shared__ int sh[128];
  int t = threadIdx.x;
  int v = (t < NSCANB) ? bsum[t] : 0;
  sh[t] = v;
  __syncthreads();
  for (int d = 1; d < 128; d <<= 1) {
    int add = (t >= d) ? sh[t - d] : 0;
    __syncthreads();
    sh[t] += add;
    __syncthreads();
  }
  if (t < NSCANB) bbase[t] = sh[t] - v;
}
__global__ void scan_c(const int* __restrict__ lscan, const int* __restrict__ counts,
                       const int* __restrict__ bbase, int* __restrict__ offsets,
                       int* __restrict__ cursor) {
  int t = threadIdx.x;
  int i = blockIdx.x * 256 + t;
  if (i == 0) offsets[0] = 0;
  if (i < NNODES) {
    int incl = lscan[i] + bbase[blockIdx.x];
    offsets[i + 1] = incl;
    cursor[i] = incl - counts[i];
  }
}

__global__ void fill_edges(const int* __restrict__ edges, int* __restrict__ cursor,
                           int* __restrict__ csr_src) {
  int i = blockIdx.x * 256 + threadIdx.x;
  if (i >= NETOT) return;
  int src, dst;
  if (i < NEDGE) { src = edges[i]; dst = edges[NEDGE + i]; }
  else { src = dst = i - NEDGE; }
  int pos = atomicAdd(&cursor[dst], 1);
  csr_src[pos] = src;
}

// ---------------- LDS-staged GEMM (m97 structure): C[M,N] = A[M,K] @ B[N,K]^T ----------------
// 128x128 block tile, BK=32, 256 thr = 4 waves, each wave 64x64 (4x4 MFMA 16x16x32).
// DOTS: fused attention-dot partials -> atomicAdd a_src/a_dst [M, N/128] (h = blockIdx.y)
template <bool DOTS, bool BIAS, bool OUTF32>
__global__ __launch_bounds__(256) void gemm_bt(const u16* __restrict__ A, const u16* __restrict__ B,
                                               const float* __restrict__ bias, void* __restrict__ Cv,
                                               const float* __restrict__ att_s,
                                               const float* __restrict__ att_d,
                                               float* __restrict__ a_srcO, float* __restrict__ a_dstO,
                                               int M, int N, int K) {
  __shared__ u16 sA[128 * 32];
  __shared__ u16 sB[128 * 32];
  int tid = threadIdx.x;
  int wv = tid >> 6;
  int lane = tid & 63;
  int quad = lane >> 4;
  int l16 = lane & 15;
  int m0 = blockIdx.x * 128;
  int n0g = blockIdx.y * 128;
  int rm = (wv >> 1) * 64;             // wave row base in tile
  int cn = (wv & 1) * 64;              // wave col base in tile

  f32x4 acc[4][4];
  #pragma unroll
  for (int mi = 0; mi < 4; ++mi)
    #pragma unroll
    for (int ni = 0; ni < 4; ++ni) acc[mi][ni] = f32x4{0.f, 0.f, 0.f, 0.f};

  for (int k0 = 0; k0 < K; k0 += 32) {
    // stage A,B tiles (128 rows x 32 cols bf16 = 8192 B each; 2 chunks of 1024 B per wave)
    #pragma unroll
    for (int q = 0; q < 2; ++q) {
      int off = (q * 4 + wv) * 1024 + lane * 16;   // byte offset in tile
      int row = off >> 6;                           // 64 B per row
      int kk = (off & 63) >> 1;                     // u16 col within row
      int rg = m0 + row; if (rg >= M) rg = M - 1;
      gl2lds16(A + (size_t)rg * K + k0 + kk, &sA[off >> 1]);
      gl2lds16(B + (size_t)(n0g + row) * K + k0 + kk, &sB[off >> 1]);
    }
    __syncthreads();
    bf16x8 af[4], bf[4];
    #pragma unroll
    for (int mi = 0; mi < 4; ++mi)
      af[mi] = *(const bf16x8*)&sA[(rm + mi * 16 + l16) * 32 + quad * 8];
    #pragma unroll
    for (int ni = 0; ni < 4; ++ni)
      bf[ni] = *(const bf16x8*)&sB[(cn + ni * 16 + l16) * 32 + quad * 8];
    #pragma unroll
    for (int mi = 0; mi < 4; ++mi)
      #pragma unroll
      for (int ni = 0; ni < 4; ++ni)
        acc[mi][ni] = __builtin_amdgcn_mfma_f32_16x16x32_bf16(af[mi], bf[ni], acc[mi][ni], 0, 0, 0);
    __syncthreads();
  }

  int h = n0g >> 7;                    // one head per 128-col block
  if (DOTS) {
    float av_s[4], av_d[4];
    #pragma unroll
    for (int ni = 0; ni < 4; ++ni) {
      int col = n0g + cn + ni * 16 + l16;
      av_s[ni] = att_s[col];
      av_d[ni] = att_d[col];
    }
    int H = N >> 7;
    #pragma unroll
    for (int mi = 0; mi < 4; ++mi) {
      #pragma unroll
      for (int r = 0; r < 4; ++r) {
        float sp = 0.f, dp = 0.f;
        #pragma unroll
        for (int ni = 0; ni < 4; ++ni) {
          sp += acc[mi][ni][r] * av_s[ni];
          dp += acc[mi][ni][r] * av_d[ni];
        }
        #pragma unroll
        for (int w = 1; w < 16; w <<= 1) {   // reduce over the 16 col-lanes
          sp += __shfl_xor(sp, w, 64);
          dp += __shfl_xor(dp, w, 64);
        }
        int orow = m0 + rm + mi * 16 + quad * 4 + r;
        if (l16 == 0 && orow < M) {
          atomicAdd(&a_srcO[(size_t)orow * H + h], sp);
          atomicAdd(&a_dstO[(size_t)orow * H + h], dp);
        }
      }
    }
  }
  #pragma unroll
  for (int ni = 0; ni < 4; ++ni) {
    int col = n0g + cn + ni * 16 + l16;
    float bv = BIAS ? bias[col] : 0.f;
    #pragma unroll
    for (int mi = 0; mi < 4; ++mi) {
      #pragma unroll
      for (int r = 0; r < 4; ++r) {
        int orow = m0 + rm + mi * 16 + quad * 4 + r;
        if (orow < M) {
          float v = acc[mi][ni][r] + bv;
          if (OUTF32) ((float*)Cv)[(size_t)orow * N + col] = v;
          else        ((u16*)Cv)[(size_t)orow * N + col] = f2bf(v);
        }
      }
    }
  }
}

// ---------------- alpha layer1 (H=8): edge-major out [NETOT][8] ----------------
// one wave per dst; lane = i*8+h (i = edge slot group); fully-coalesced 256-B writes.
__global__ __launch_bounds__(256) void alpha1_k(const int* __restrict__ offs,
                                                const int* __restrict__ csr_src,
                                                const float* __restrict__ a_src,
                                                const float* __restrict__ a_dst,
                                                float* __restrict__ alpha) {
  int wv = threadIdx.x >> 6;
  int dst = blockIdx.x * 4 + wv;
  if (dst >= NNODES) return;
  int l = threadIdx.x & 63;
  int h = l & 7, i = l >> 3;
  int off = offs[dst];
  int deg = offs[dst + 1] - off;
  const int* srcs = csr_src + off;
  float ad = a_dst[dst * 8 + h];
  float m = -1e30f, ssum = 0.f;
  float* out = alpha + (size_t)off * 8;
  if (deg <= 64) {
    int sl = srcs[l < deg ? l : deg - 1];       // coalesced preload
    float ev[8];
    #pragma unroll
    for (int t = 0; t < 8; ++t) {
      int jj = i + t * 8;
      float e = -1e30f;
      if (jj < deg) {
        int s = __shfl(sl, jj, 64);
        e = lrelu(a_src[s * 8 + h] + ad);       // 8 h-lanes share s: 32-B segment
      }
      ev[t] = e;
      float nm = fmaxf(m, e);
      ssum = ssum * __expf(m - nm) + ((jj < deg) ? __expf(e - nm) : 0.f);
      m = nm;
    }
    #pragma unroll
    for (int w = 8; w < 64; w <<= 1) {          // reduce over i (lane bits 3..5)
      float om = __shfl_xor(m, w, 64);
      float os = __shfl_xor(ssum, w, 64);
      float nm = fmaxf(m, om);
      ssum = ssum * __expf(m - nm) + os * __expf(om - nm);
      m = nm;
    }
    float inv = 1.f / (ssum + 1e-16f);
    #pragma unroll
    for (int t = 0; t < 8; ++t) {
      int jj = i + t * 8;
      if (jj < deg) out[(size_t)jj * 8 + h] = __expf(ev[t] - m) * inv;
    }
  } else {
    for (int j = i; j < deg; j += 8) {
      int s = srcs[j];
      float e = lrelu(a_src[s * 8 + h] + ad);
      float nm = fmaxf(m, e);
      ssum = ssum * __expf(m - nm) + __expf(e - nm);
      m = nm;
    }
    #pragma unroll
    for (int w = 8; w < 64; w <<= 1) {
      float om = __shfl_xor(m, w, 64);
      float os = __shfl_xor(ssum, w, 64);
      float nm = fmaxf(m, om);
      ssum = ssum * __expf(m - nm) + os * __expf(om - nm);
      m = nm;
    }
    float inv = 1.f / (ssum + 1e-16f);
    for (int j = i; j < deg; j += 8) {
      int s = srcs[j];
      float e = lrelu(a_src[s * 8 + h] + ad);
      out[(size_t)j * 8 + h] = __expf(e - m) * inv;
    }
  }
}

// ---------------- alpha layer2 (H=1): flat out [NETOT] ----------------
__global__ __launch_bounds__(256) void alpha2_k(const int* __restrict__ offs,
                                                const int* __restrict__ csr_src,
                                                const float* __restrict__ a_src,
                                                const float* __restrict__ a_dst,
                                                float* __restrict__ alpha) {
  int wv = threadIdx.x >> 6;
  int dst = blockIdx.x * 4 + wv;
  if (dst >= NNODES) return;
  int l = threadIdx.x & 63;
  int off = offs[dst];
  int deg = offs[dst + 1] - off;
  float ad = a_dst[dst];
  if (deg <= 64) {
    float e = -1e30f;
    if (l < deg) e = lrelu(a_src[csr_src[off + l]] + ad);
    float m = e;
    #pragma unroll
    for (int w = 1; w < 64; w <<= 1) m = fmaxf(m, __shfl_xor(m, w, 64));
    float p = (l < deg) ? __expf(e - m) : 0.f;
    float ssum = p;
    #pragma unroll
    for (int w = 1; w < 64; w <<= 1) ssum += __shfl_xor(ssum, w, 64);
    float inv = 1.f / (ssum + 1e-16f);
    if (l < deg) alpha[off + l] = p * inv;
  } else {
    float m = -1e30f, ssum = 0.f;
    for (int j = l; j < deg; j += 64) {
      float e = lrelu(a_src[csr_src[off + j]] + ad);
      float nm = fmaxf(m, e);
      ssum = ssum * __expf(m - nm) + __expf(e - nm);
      m = nm;
    }
    #pragma unroll
    for (int w = 1; w < 64; w <<= 1) {
      float om = __shfl_xor(m, w, 64);
      float os = __shfl_xor(ssum, w, 64);
      float nm = fmaxf(m, om);
      ssum = ssum * __expf(m - nm) + os * __expf(om - nm);
      m = nm;
    }
    float inv = 1.f / (ssum + 1e-16f);
    for (int j = l; j < deg; j += 64) {
      float e = lrelu(a_src[csr_src[off + j]] + ad);
      alpha[off + j] = __expf(e - m) * inv;
    }
  }
}

// ---------------- SpMM layer1: all 8 heads per wave, node-major xp1 ----------------
// wave per dst; lane l owns channels l*16..l*16+15 (head = l>>3). Per edge: full
// 2048-B contiguous row gather (2x16 B per lane); alpha via one 32-B line (edge-major).
// No cross-lane reduction. Edge indices preloaded (64/chunk) -> shfl -> independent gathers.
__global__ __launch_bounds__(256) void spmm1(const int* __restrict__ offs,
                                             const int* __restrict__ csr_src,
                                             const float* __restrict__ alp,
                                             const u16* __restrict__ xp1,
                                             const float* __restrict__ bias,
                                             u16* __restrict__ out) {
  int wv = threadIdx.x >> 6;
  int dst = blockIdx.x * 4 + wv;
  if (dst >= NNODES) return;
  int l = threadIdx.x & 63;
  int h = l >> 3;
  int off = offs[dst];
  int deg = offs[dst + 1] - off;
  const int* srcs = csr_src + off;
  const float* alb = alp + (size_t)off * 8 + h;
  float acc[16];
  #pragma unroll
  for (int k = 0; k < 16; ++k) acc[k] = 0.f;
  for (int b0 = 0; b0 < deg; b0 += 64) {
    int cnt = deg - b0; if (cnt > 64) cnt = 64;
    int sl = srcs[b0 + (l < cnt ? l : cnt - 1)];   // coalesced preload
    for (int j = 0; j < cnt; ++j) {
      int s = __shfl(sl, j, 64);
      float w = alb[(size_t)(b0 + j) * 8];         // 32-B line broadcast
      const u16* row = xp1 + (size_t)s * 1024 + l * 16;
      bf16x8 f0 = *(const bf16x8*)row;
      bf16x8 f1 = *(const bf16x8*)(row + 8);
      #pragma unroll
      for (int k = 0; k < 8; ++k) acc[k] += w * bf2f((u16)f0[k]);
      #pragma unroll
      for (int k = 0; k < 8; ++k) acc[k + 8] += w * bf2f((u16)f1[k]);
    }
  }
  int cg = l * 16;
  const f32x4* b4 = (const f32x4*)(bias + cg);
  f32x4 bb[4] = {b4[0], b4[1], b4[2], b4[3]};
  union { u16 a[16]; uint4 v[2]; } o;
  #pragma unroll
  for (int k = 0; k < 16; ++k) o.a[k] = f2bf(fmaxf(acc[k] + bb[k >> 2][k & 3], 0.f));
  uint4* op = (uint4*)(out + (size_t)dst * 1024 + cg);
  op[0] = o.v[0];
  op[1] = o.v[1];
}

// ---------------- SpMM layer2 (H=1, C=128) ----------------
__global__ __launch_bounds__(256) void spmm2(const int* __restrict__ offs,
                                             const int* __restrict__ csr_src,
                                             const float* __restrict__ alpha,
                                             const u16* __restrict__ xp2,
                                             const float* __restrict__ bias,
                                             u16* __restrict__ out) {
  int wv = threadIdx.x >> 6;
  int dst = blockIdx.x * 4 + wv;
  if (dst >= NNODES) return;
  int l = threadIdx.x & 63;
  int e = l >> 4, c = l & 15;
  int off = offs[dst];
  int deg = offs[dst + 1] - off;
  const float* al = alpha + off;
  const int* srcs = csr_src + off;
  const u16* base = xp2 + c * 8;
  float acc[8] = {0.f, 0.f, 0.f, 0.f, 0.f, 0.f, 0.f, 0.f};
  for (int b0 = 0; b0 < deg; b0 += 64) {
    int cnt = deg - b0; if (cnt > 64) cnt = 64;
    int sl = srcs[b0 + (l < cnt ? l : cnt - 1)];
    float wl = (l < cnt) ? al[b0 + l] : 0.f;
    int ng = (cnt + 3) >> 2;
    for (int g = 0; g < ng; ++g) {
      int slot = g * 4 + e;
      int s = __shfl(sl, slot, 64);
      float w = __shfl(wl, slot, 64);
      bf16x8 f = *(const bf16x8*)(base + (size_t)s * 128);
      #pragma unroll
      for (int k = 0; k < 8; ++k) acc[k] += w * bf2f((u16)f[k]);
    }
  }
  #pragma unroll
  for (int k = 0; k < 8; ++k) {
    acc[k] += __shfl_xor(acc[k], 16, 64);
    acc[k] += __shfl_xor(acc[k], 32, 64);
  }
  if (e == 0) {
    int cg = c * 8;
    union { u16 a[8]; uint4 v; } o;
    #pragma unroll
    for (int k = 0; k < 8; ++k) o.a[k] = f2bf(fmaxf(acc[k] + bias[cg + k], 0.f));
    *(uint4*)(out + (size_t)dst * 128 + cg) = o.v;
  }
}

// ---------------- launch ----------------
extern "C" void kernel_launch(void* const* d_in, const int* in_sizes, int n_in,
                              void* d_out, int out_size, void* d_ws, size_t ws_size,
                              hipStream_t stream) {
  const float* cons    = (const float*)d_in[0];
  const float* cols    = (const float*)d_in[1];
  const float* node_W  = (const float*)d_in[2];
  const float* node_b  = (const float*)d_in[3];
  const float* col_W   = (const float*)d_in[4];
  const float* col_b   = (const float*)d_in[5];
  const float* W1      = (const float*)d_in[6];
  const float* att_s1  = (const float*)d_in[7];
  const float* att_d1  = (const float*)d_in[8];
  const float* b1      = (const float*)d_in[9];
  const float* W2      = (const float*)d_in[10];
  const float* att_s2  = (const float*)d_in[11];
  const float* att_d2  = (const float*)d_in[12];
  const float* b2      = (const float*)d_in[13];
  const float* out_W   = (const float*)d_in[14];
  const float* out_b   = (const float*)d_in[15];
  const int* edges     = (const int*)d_in[16];

  char* p = (char*)d_ws;
  auto alloc = [&](size_t bytes) {
    char* r = p;
    p += (bytes + 255) & ~(size_t)255;
    return r;
  };
  u16* emb0    = (u16*)alloc((size_t)NNODES * 128 * 2);        // bf16
  u16* xp1     = (u16*)alloc((size_t)NNODES * 1024 * 2);       // bf16, node-major
  u16* emb2    = (u16*)alloc((size_t)NNODES * 1024 * 2);       // bf16
  u16* xp2     = (u16*)alloc((size_t)NNODES * 128 * 2);        // bf16
  u16* emb3    = (u16*)alloc((size_t)NNODES * 128 * 2);        // bf16
  u16* Wbf     = (u16*)alloc((size_t)(W1N + W2N + OWN) * 2);   // W1|W2|out_W contiguous
  // ---- contiguous zero region: as1, ad1, as2, ad2, counts ----
  float* as1   = (float*)alloc((size_t)NNODES * 8 * 4);        // 640000 B (256-mult)
  float* ad1   = (float*)alloc((size_t)NNODES * 8 * 4);        // 640000 B
  float* as2   = (float*)alloc((size_t)NNODES * 4);            // pads to 80128 B
  float* ad2   = (float*)alloc((size_t)NNODES * 4);            // pads to 80128 B
  int* counts  = (int*)alloc((size_t)NNODES * 4);              // pads to 80128 B
  size_t zspan = (char*)(counts + NNODES) - (char*)as1;
  // ---- end zero region ----
  float* alp1  = (float*)alloc((size_t)NETOT * 8 * 4);         // edge-major [NETOT][8]
  float* alp2  = (float*)alloc((size_t)NETOT * 4);
  int* offs    = (int*)alloc((size_t)(NNODES + 1) * 4);
  int* cursor  = (int*)alloc((size_t)NNODES * 4);
  int* csrsrc  = (int*)alloc((size_t)NETOT * 4);
  int* lscan   = (int*)alloc((size_t)NSCANB * 256 * 4);
  int* bsum    = (int*)alloc((size_t)NSCANB * 4);
  int* bbase   = (int*)alloc((size_t)NSCANB * 4);

  u16* W1bf = Wbf;
  u16* W2bf = Wbf + W1N;
  u16* oWbf = Wbf + W1N + W2N;

  hipMemsetAsync(as1, 0, zspan, stream);

  // CSR build
  count_edges<<<(NETOT + 255) / 256, 256, 0, stream>>>(edges, counts);
  scan_a<<<NSCANB, 256, 0, stream>>>(counts, lscan, bsum);
  scan_b<<<1, 128, 0, stream>>>(bsum, bbase);
  scan_c<<<NSCANB, 256, 0, stream>>>(lscan, counts, bbase, offs, cursor);
  fill_edges<<<(NETOT + 255) / 256, 256, 0, stream>>>(edges, cursor, csrsrc);

  // layer 0 embed + weight conversions, fused
  prep<<<(EMB0N + W1N + W2N + OWN + 255) / 256, 256, 0, stream>>>(
      cons, cols, node_W, node_b, col_W, col_b, W1, W2, out_W, emb0, Wbf);

  // GAT layer 1: GEMM (fused dots, row-major out) -> alpha (edge-major) -> SpMM (all heads)
  gemm_bt<true, false, false><<<dim3((NNODES + 127) / 128, 1024 / 128), 256, 0, stream>>>(
      emb0, W1bf, nullptr, xp1, att_s1, att_d1, as1, ad1, NNODES, 1024, 128);
  alpha1_k<<<(NNODES + 3) / 4, 256, 0, stream>>>(offs, csrsrc, as1, ad1, alp1);
  spmm1<<<(NNODES + 3) / 4, 256, 0, stream>>>(offs, csrsrc, alp1, xp1, b1, emb2);

  // GAT layer 2: GEMM (fused dots) -> alpha -> SpMM
  gemm_bt<true, false, false><<<dim3((NNODES + 127) / 128, 1), 256, 0, stream>>>(
      emb2, W2bf, nullptr, xp2, att_s2, att_d2, as2, ad2, NNODES, 128, 1024);
  alpha2_k<<<(NNODES + 3) / 4, 256, 0, stream>>>(offs, csrsrc, as2, ad2, alp2);
  spmm2<<<(NNODES + 3) / 4, 256, 0, stream>>>(offs, csrsrc, alp2, xp2, b2, emb3);

  // output projection: rows 10000..19999, f32 out with bias
  gemm_bt<false, true, true><<<dim3((NCOLSN + 127) / 128, 1), 256, 0, stream>>>(
      emb3 + (size_t)NCONS * 128, oWbf, out_b, d_out, nullptr, nullptr, nullptr, nullptr,
      NCOLSN, 128, 128);
}

// Round 8
// 321.538 us; speedup vs baseline: 1.4787x; 1.0029x over previous
//
#include <hip/hip_runtime.h>

// ---------------- problem constants ----------------
#define NCONS 10000
#define NCOLSN 10000
#define NNODES 20000         // NCONS + NCOLSN
#define NEDGE 200000
#define NETOT 220000         // NEDGE + NNODES self loops
#define NEG_SLOPE 0.2f
#define NSCANB 79            // ceil(NNODES/256)

typedef unsigned short u16;
typedef __attribute__((ext_vector_type(8))) short bf16x8;
typedef __attribute__((ext_vector_type(4))) float f32x4;

__device__ __forceinline__ float bf2f(u16 u) {
  return __uint_as_float(((unsigned int)u) << 16);
}
__device__ __forceinline__ u16 f2bf(float f) {
  unsigned int x = __float_as_uint(f);
  return (u16)((x + 0x7fffu + ((x >> 16) & 1u)) >> 16);
}
__device__ __forceinline__ float lrelu(float v) {
  return v >= 0.f ? v : NEG_SLOPE * v;
}
// async global->LDS, 16 B per lane; LDS dest must be wave-uniform base + lane*16
__device__ __forceinline__ void gl2lds16(const u16* g, u16* l) {
  __builtin_amdgcn_global_load_lds(
      (const __attribute__((address_space(1))) unsigned int*)g,
      (__attribute__((address_space(3))) unsigned int*)l, 16, 0, 0);
}
__device__ __forceinline__ float readlane_f(float v, int j) {
  return __uint_as_float(__builtin_amdgcn_readlane(__float_as_uint(v), j));
}

#define W1N (1024 * 128)
#define W2N (128 * 1024)
#define OWN (128 * 128)
#define EMB0N (NNODES * 128)

// ---------------- fused: layer-0 embed + weight f32->bf16 conversion ----------------
__global__ void prep(const float* __restrict__ cons, const float* __restrict__ cols,
                     const float* __restrict__ nW, const float* __restrict__ nb,
                     const float* __restrict__ cW, const float* __restrict__ cb,
                     const float* __restrict__ W1, const float* __restrict__ W2,
                     const float* __restrict__ oW, u16* __restrict__ emb,
                     u16* __restrict__ Wbf) {
  int idx = blockIdx.x * 256 + threadIdx.x;
  if (idx < EMB0N) {
    int row = idx >> 7, o = idx & 127;
    float acc;
    if (row < NCONS) {
      acc = nb[o];
      #pragma unroll
      for (int k = 0; k < 4; ++k)
        acc += cons[row * 4 + k] * (nW[o * 8 + k] + nW[o * 8 + 4 + k]);
    } else {
      int r = row - NCONS;
      acc = cb[o];
      #pragma unroll
      for (int k = 0; k < 8; ++k)
        acc += cols[r * 8 + k] * (cW[o * 16 + k] + cW[o * 16 + 8 + k]);
    }
    emb[idx] = f2bf(fmaxf(acc, 0.f));
  } else {
    int i = idx - EMB0N;
    if (i >= W1N + W2N + OWN) return;
    float v;
    if (i < W1N) v = W1[i];
    else if (i < W1N + W2N) v = W2[i - W1N];
    else v = oW[i - W1N - W2N];
    Wbf[i] = f2bf(v);
  }
}

// ---------------- CSR build ----------------
__global__ void count_edges(const int* __restrict__ edges, int* __restrict__ counts) {
  int i = blockIdx.x * 256 + threadIdx.x;
  if (i >= NETOT) return;
  int dst = (i < NEDGE) ? edges[NEDGE + i] : (i - NEDGE);
  atomicAdd(&counts[dst], 1);
}

__global__ void scan_a(const int* __restrict__ counts, int* __restrict__ lscan,
                       int* __restrict__ bsum) {
  __shared__ int sh[256];
  int t = threadIdx.x;
  int i = blockIdx.x * 256 + t;
  int v = (i < NNODES) ? counts[i] : 0;
  sh[t] = v;
  __syncthreads();
  for (int d = 1; d < 256; d <<= 1) {
    int add = (t >= d) ? sh[t - d] : 0;
    __syncthreads();
    sh[t] += add;
    __syncthreads();
  }
  lscan[i] = sh[t];
  if (t == 255) bsum[blockIdx.x] = sh[255];
}
__global__ void scan_b(const int* __restrict__ bsum, int* __restrict__ bbase) {
  __shared__ int sh[128];
  int t = threadIdx.x;
  int v = (t < NSCANB) ? bsum[t] : 0;
  sh[t] = v;
  __syncthreads();
  for (int d = 1; d < 128; d <<= 1) {
    int add = (t >= d) ? sh[t - d] : 0;
    __syncthreads();
    sh[t] += add;
    __syncthreads();
  }
  if (t < NSCANB) bbase[t] = sh[t] - v;
}
__global__ void scan_c(const int* __restrict__ lscan, const int* __restrict__ counts,
                       const int* __restrict__ bbase, int* __restrict__ offsets,
                       int* __restrict__ cursor) {
  int t = threadIdx.x;
  int i = blockIdx.x * 256 + t;
  if (i == 0) offsets[0] = 0;
  if (i < NNODES) {
    int incl = lscan[i] + bbase[blockIdx.x];
    offsets[i + 1] = incl;
    cursor[i] = incl - counts[i];
  }
}

__global__ void fill_edges(const int* __restrict__ edges, int* __restrict__ cursor,
                           int* __restrict__ csr_src) {
  int i = blockIdx.x * 256 + threadIdx.x;
  if (i >= NETOT) return;
  int src, dst;
  if (i < NEDGE) { src = edges[i]; dst = edges[NEDGE + i]; }
  else { src = dst = i - NEDGE; }
  int pos = atomicAdd(&cursor[dst], 1);
  csr_src[pos] = src;
}

// ---------------- LDS-staged GEMM (m97 structure): C[M,N] = A[M,K] @ B[N,K]^T ----------------
// 128x128 block tile, BK=32, 256 thr = 4 waves, each wave 64x64 (4x4 MFMA 16x16x32).
// DOTS: fused attention-dot partials -> atomicAdd a_src/a_dst [M, N/128] (h = blockIdx.y)
// HM:   head-major store C[(col>>7)][row][col&127], slice stride NNODES*128
template <bool DOTS, bool HM, bool BIAS, bool OUTF32>
__global__ __launch_bounds__(256) void gemm_bt(const u16* __restrict__ A, const u16* __restrict__ B,
                                               const float* __restrict__ bias, void* __restrict__ Cv,
                                               const float* __restrict__ att_s,
                                               const float* __restrict__ att_d,
                                               float* __restrict__ a_srcO, float* __restrict__ a_dstO,
                                               int M, int N, int K) {
  __shared__ u16 sA[128 * 32];
  __shared__ u16 sB[128 * 32];
  int tid = threadIdx.x;
  int wv = tid >> 6;
  int lane = tid & 63;
  int quad = lane >> 4;
  int l16 = lane & 15;
  int m0 = blockIdx.x * 128;
  int n0g = blockIdx.y * 128;
  int rm = (wv >> 1) * 64;             // wave row base in tile
  int cn = (wv & 1) * 64;              // wave col base in tile

  f32x4 acc[4][4];
  #pragma unroll
  for (int mi = 0; mi < 4; ++mi)
    #pragma unroll
    for (int ni = 0; ni < 4; ++ni) acc[mi][ni] = f32x4{0.f, 0.f, 0.f, 0.f};

  for (int k0 = 0; k0 < K; k0 += 32) {
    // stage A,B tiles (128 rows x 32 cols bf16 = 8192 B each; 2 chunks of 1024 B per wave)
    #pragma unroll
    for (int q = 0; q < 2; ++q) {
      int off = (q * 4 + wv) * 1024 + lane * 16;   // byte offset in tile
      int row = off >> 6;                           // 64 B per row
      int kk = (off & 63) >> 1;                     // u16 col within row
      int rg = m0 + row; if (rg >= M) rg = M - 1;
      gl2lds16(A + (size_t)rg * K + k0 + kk, &sA[off >> 1]);
      gl2lds16(B + (size_t)(n0g + row) * K + k0 + kk, &sB[off >> 1]);
    }
    __syncthreads();
    bf16x8 af[4], bf[4];
    #pragma unroll
    for (int mi = 0; mi < 4; ++mi)
      af[mi] = *(const bf16x8*)&sA[(rm + mi * 16 + l16) * 32 + quad * 8];
    #pragma unroll
    for (int ni = 0; ni < 4; ++ni)
      bf[ni] = *(const bf16x8*)&sB[(cn + ni * 16 + l16) * 32 + quad * 8];
    #pragma unroll
    for (int mi = 0; mi < 4; ++mi)
      #pragma unroll
      for (int ni = 0; ni < 4; ++ni)
        acc[mi][ni] = __builtin_amdgcn_mfma_f32_16x16x32_bf16(af[mi], bf[ni], acc[mi][ni], 0, 0, 0);
    __syncthreads();
  }

  int h = n0g >> 7;                    // one head per 128-col block
  if (DOTS) {
    float av_s[4], av_d[4];
    #pragma unroll
    for (int ni = 0; ni < 4; ++ni) {
      int col = n0g + cn + ni * 16 + l16;
      av_s[ni] = att_s[col];
      av_d[ni] = att_d[col];
    }
    int H = N >> 7;
    #pragma unroll
    for (int mi = 0; mi < 4; ++mi) {
      #pragma unroll
      for (int r = 0; r < 4; ++r) {
        float sp = 0.f, dp = 0.f;
        #pragma unroll
        for (int ni = 0; ni < 4; ++ni) {
          sp += acc[mi][ni][r] * av_s[ni];
          dp += acc[mi][ni][r] * av_d[ni];
        }
        #pragma unroll
        for (int w = 1; w < 16; w <<= 1) {   // reduce over the 16 col-lanes
          sp += __shfl_xor(sp, w, 64);
          dp += __shfl_xor(dp, w, 64);
        }
        int orow = m0 + rm + mi * 16 + quad * 4 + r;
        if (l16 == 0 && orow < M) {
          atomicAdd(&a_srcO[(size_t)orow * H + h], sp);
          atomicAdd(&a_dstO[(size_t)orow * H + h], dp);
        }
      }
    }
  }
  #pragma unroll
  for (int ni = 0; ni < 4; ++ni) {
    int col = n0g + cn + ni * 16 + l16;
    float bv = BIAS ? bias[col] : 0.f;
    #pragma unroll
    for (int mi = 0; mi < 4; ++mi) {
      #pragma unroll
      for (int r = 0; r < 4; ++r) {
        int orow = m0 + rm + mi * 16 + quad * 4 + r;
        if (orow < M) {
          float v = acc[mi][ni][r] + bv;
          if (OUTF32) {
            ((float*)Cv)[(size_t)orow * N + col] = v;
          } else if (HM) {
            ((u16*)Cv)[(size_t)h * ((size_t)NNODES * 128) + (size_t)orow * 128 + (col & 127)] = f2bf(v);
          } else {
            ((u16*)Cv)[(size_t)orow * N + col] = f2bf(v);
          }
        }
      }
    }
  }
}

// ---------------- alpha layer1 (H=8): edge-major out [NETOT][8] ----------------
// one wave per dst; lane = i*8+h (i = edge slot group); fully-coalesced 256-B writes.
__global__ __launch_bounds__(256) void alpha1_k(const int* __restrict__ offs,
                                                const int* __restrict__ csr_src,
                                                const float* __restrict__ a_src,
                                                const float* __restrict__ a_dst,
                                                float* __restrict__ alpha) {
  int wv = threadIdx.x >> 6;
  int dst = blockIdx.x * 4 + wv;
  if (dst >= NNODES) return;
  int l = threadIdx.x & 63;
  int h = l & 7, i = l >> 3;
  int off = offs[dst];
  int deg = offs[dst + 1] - off;
  const int* srcs = csr_src + off;
  float ad = a_dst[dst * 8 + h];
  float m = -1e30f, ssum = 0.f;
  float* out = alpha + (size_t)off * 8;
  if (deg <= 64) {
    int sl = srcs[l < deg ? l : deg - 1];       // coalesced preload
    float ev[8];
    #pragma unroll
    for (int t = 0; t < 8; ++t) {
      int jj = i + t * 8;
      float e = -1e30f;
      if (jj < deg) {
        int s = __builtin_amdgcn_readlane(sl, jj);
        e = lrelu(a_src[s * 8 + h] + ad);       // 8 h-lanes share s: 32-B segment
      }
      ev[t] = e;
      float nm = fmaxf(m, e);
      ssum = ssum * __expf(m - nm) + ((jj < deg) ? __expf(e - nm) : 0.f);
      m = nm;
    }
    #pragma unroll
    for (int w = 8; w < 64; w <<= 1) {          // reduce over i (lane bits 3..5)
      float om = __shfl_xor(m, w, 64);
      float os = __shfl_xor(ssum, w, 64);
      float nm = fmaxf(m, om);
      ssum = ssum * __expf(m - nm) + os * __expf(om - nm);
      m = nm;
    }
    float inv = 1.f / (ssum + 1e-16f);
    #pragma unroll
    for (int t = 0; t < 8; ++t) {
      int jj = i + t * 8;
      if (jj < deg) out[(size_t)jj * 8 + h] = __expf(ev[t] - m) * inv;
    }
  } else {
    for (int j = i; j < deg; j += 8) {
      int s = srcs[j];
      float e = lrelu(a_src[s * 8 + h] + ad);
      float nm = fmaxf(m, e);
      ssum = ssum * __expf(m - nm) + __expf(e - nm);
      m = nm;
    }
    #pragma unroll
    for (int w = 8; w < 64; w <<= 1) {
      float om = __shfl_xor(m, w, 64);
      float os = __shfl_xor(ssum, w, 64);
      float nm = fmaxf(m, om);
      ssum = ssum * __expf(m - nm) + os * __expf(om - nm);
      m = nm;
    }
    float inv = 1.f / (ssum + 1e-16f);
    for (int j = i; j < deg; j += 8) {
      int s = srcs[j];
      float e = lrelu(a_src[s * 8 + h] + ad);
      out[(size_t)j * 8 + h] = __expf(e - m) * inv;
    }
  }
}

// ---------------- alpha layer2 (H=1): flat out [NETOT] ----------------
__global__ __launch_bounds__(256) void alpha2_k(const int* __restrict__ offs,
                                                const int* __restrict__ csr_src,
                                                const float* __restrict__ a_src,
                                                const float* __restrict__ a_dst,
                                                float* __restrict__ alpha) {
  int wv = threadIdx.x >> 6;
  int dst = blockIdx.x * 4 + wv;
  if (dst >= NNODES) return;
  int l = threadIdx.x & 63;
  int off = offs[dst];
  int deg = offs[dst + 1] - off;
  float ad = a_dst[dst];
  if (deg <= 64) {
    float e = -1e30f;
    if (l < deg) e = lrelu(a_src[csr_src[off + l]] + ad);
    float m = e;
    #pragma unroll
    for (int w = 1; w < 64; w <<= 1) m = fmaxf(m, __shfl_xor(m, w, 64));
    float p = (l < deg) ? __expf(e - m) : 0.f;
    float ssum = p;
    #pragma unroll
    for (int w = 1; w < 64; w <<= 1) ssum += __shfl_xor(ssum, w, 64);
    float inv = 1.f / (ssum + 1e-16f);
    if (l < deg) alpha[off + l] = p * inv;
  } else {
    float m = -1e30f, ssum = 0.f;
    for (int j = l; j < deg; j += 64) {
      float e = lrelu(a_src[csr_src[off + j]] + ad);
      float nm = fmaxf(m, e);
      ssum = ssum * __expf(m - nm) + __expf(e - nm);
      m = nm;
    }
    #pragma unroll
    for (int w = 1; w < 64; w <<= 1) {
      float om = __shfl_xor(m, w, 64);
      float os = __shfl_xor(ssum, w, 64);
      float nm = fmaxf(m, om);
      ssum = ssum * __expf(m - nm) + os * __expf(om - nm);
      m = nm;
    }
    float inv = 1.f / (ssum + 1e-16f);
    for (int j = l; j < deg; j += 64) {
      float e = lrelu(a_src[csr_src[off + j]] + ad);
      alpha[off + j] = __expf(e - m) * inv;
    }
  }
}

// ---------------- SpMM layer1: head-sliced xp1h + scalar-path addressing ----------------
// wave per (dst, head); h = blockIdx.x & 7 -> XCD affinity on 5 MB head slice (L2-resident).
// Edge chunk (srcs, alpha) preloaded into VGPR lanes; per edge v_readlane -> SGPR index ->
// scalar address path. Lane owns channels 2l,2l+1 (4 B): whole wave = one 256-B row request.
// No cross-lane reduction.
__global__ __launch_bounds__(256) void spmm1(const int* __restrict__ offs,
                                             const int* __restrict__ csr_src,
                                             const float* __restrict__ alp,
                                             const u16* __restrict__ xp1h,
                                             const float* __restrict__ bias,
                                             u16* __restrict__ out) {
  int h = blockIdx.x & 7;
  int wv = threadIdx.x >> 6;
  int dst = (blockIdx.x >> 3) * 4 + wv;
  if (dst >= NNODES) return;
  int l = threadIdx.x & 63;
  int off = offs[dst];
  int deg = offs[dst + 1] - off;
  const int* srcs = csr_src + off;
  const float* alb = alp + (size_t)off * 8 + h;
  const u16* base = xp1h + (size_t)h * ((size_t)NNODES * 128) + l * 2;
  float a0 = 0.f, a1 = 0.f;
  for (int b0 = 0; b0 < deg; b0 += 64) {
    int cnt = deg - b0; if (cnt > 64) cnt = 64;
    int sv = srcs[b0 + (l < cnt ? l : cnt - 1)];        // coalesced preload
    float av = (l < cnt) ? alb[(size_t)(b0 + l) * 8] : 0.f;
    int j = 0;
    for (; j + 4 <= cnt; j += 4) {
      #pragma unroll
      for (int t = 0; t < 4; ++t) {
        int s = __builtin_amdgcn_readlane(sv, j + t);   // SGPR
        float w = readlane_f(av, j + t);                // SGPR
        ushort2 u = *(const ushort2*)(base + (size_t)s * 128);
        a0 += w * bf2f(u.x);
        a1 += w * bf2f(u.y);
      }
    }
    for (; j < cnt; ++j) {
      int s = __builtin_amdgcn_readlane(sv, j);
      float w = readlane_f(av, j);
      ushort2 u = *(const ushort2*)(base + (size_t)s * 128);
      a0 += w * bf2f(u.x);
      a1 += w * bf2f(u.y);
    }
  }
  int cg = h * 128 + l * 2;
  ushort2 o;
  o.x = f2bf(fmaxf(a0 + bias[cg], 0.f));
  o.y = f2bf(fmaxf(a1 + bias[cg + 1], 0.f));
  *(ushort2*)(out + (size_t)dst * 1024 + cg) = o;
}

// ---------------- SpMM layer2 (H=1, C=128): same scalar-path structure ----------------
__global__ __launch_bounds__(256) void spmm2(const int* __restrict__ offs,
                                             const int* __restrict__ csr_src,
                                             const float* __restrict__ alpha,
                                             const u16* __restrict__ xp2,
                                             const float* __restrict__ bias,
                                             u16* __restrict__ out) {
  int wv = threadIdx.x >> 6;
  int dst = blockIdx.x * 4 + wv;
  if (dst >= NNODES) return;
  int l = threadIdx.x & 63;
  int off = offs[dst];
  int deg = offs[dst + 1] - off;
  const int* srcs = csr_src + off;
  const float* al = alpha + off;
  const u16* base = xp2 + l * 2;
  float a0 = 0.f, a1 = 0.f;
  for (int b0 = 0; b0 < deg; b0 += 64) {
    int cnt = deg - b0; if (cnt > 64) cnt = 64;
    int sv = srcs[b0 + (l < cnt ? l : cnt - 1)];
    float av = (l < cnt) ? al[b0 + l] : 0.f;
    int j = 0;
    for (; j + 4 <= cnt; j += 4) {
      #pragma unroll
      for (int t = 0; t < 4; ++t) {
        int s = __builtin_amdgcn_readlane(sv, j + t);
        float w = readlane_f(av, j + t);
        ushort2 u = *(const ushort2*)(base + (size_t)s * 128);
        a0 += w * bf2f(u.x);
        a1 += w * bf2f(u.y);
      }
    }
    for (; j < cnt; ++j) {
      int s = __builtin_amdgcn_readlane(sv, j);
      float w = readlane_f(av, j);
      ushort2 u = *(const ushort2*)(base + (size_t)s * 128);
      a0 += w * bf2f(u.x);
      a1 += w * bf2f(u.y);
    }
  }
  int cg = l * 2;
  ushort2 o;
  o.x = f2bf(fmaxf(a0 + bias[cg], 0.f));
  o.y = f2bf(fmaxf(a1 + bias[cg + 1], 0.f));
  *(ushort2*)(out + (size_t)dst * 128 + cg) = o;
}

// ---------------- launch ----------------
extern "C" void kernel_launch(void* const* d_in, const int* in_sizes, int n_in,
                              void* d_out, int out_size, void* d_ws, size_t ws_size,
                              hipStream_t stream) {
  const float* cons    = (const float*)d_in[0];
  const float* cols    = (const float*)d_in[1];
  const float* node_W  = (const float*)d_in[2];
  const float* node_b  = (const float*)d_in[3];
  const float* col_W   = (const float*)d_in[4];
  const float* col_b   = (const float*)d_in[5];
  const float* W1      = (const float*)d_in[6];
  const float* att_s1  = (const float*)d_in[7];
  const float* att_d1  = (const float*)d_in[8];
  const float* b1      = (const float*)d_in[9];
  const float* W2      = (const float*)d_in[10];
  const float* att_s2  = (const float*)d_in[11];
  const float* att_d2  = (const float*)d_in[12];
  const float* b2      = (const float*)d_in[13];
  const float* out_W   = (const float*)d_in[14];
  const float* out_b   = (const float*)d_in[15];
  const int* edges     = (const int*)d_in[16];

  char* p = (char*)d_ws;
  auto alloc = [&](size_t bytes) {
    char* r = p;
    p += (bytes + 255) & ~(size_t)255;
    return r;
  };
  u16* emb0    = (u16*)alloc((size_t)NNODES * 128 * 2);        // bf16
  u16* xp1h    = (u16*)alloc((size_t)8 * NNODES * 128 * 2);    // bf16, head-major slices
  u16* emb2    = (u16*)alloc((size_t)NNODES * 1024 * 2);       // bf16
  u16* xp2     = (u16*)alloc((size_t)NNODES * 128 * 2);        // bf16
  u16* emb3    = (u16*)alloc((size_t)NNODES * 128 * 2);        // bf16
  u16* Wbf     = (u16*)alloc((size_t)(W1N + W2N + OWN) * 2);   // W1|W2|out_W contiguous
  // ---- contiguous zero region: as1, ad1, as2, ad2, counts ----
  float* as1   = (float*)alloc((size_t)NNODES * 8 * 4);        // 640000 B (256-mult)
  float* ad1   = (float*)alloc((size_t)NNODES * 8 * 4);        // 640000 B
  float* as2   = (float*)alloc((size_t)NNODES * 4);            // pads to 80128 B
  float* ad2   = (float*)alloc((size_t)NNODES * 4);            // pads to 80128 B
  int* counts  = (int*)alloc((size_t)NNODES * 4);              // pads to 80128 B
  size_t zspan = (char*)(counts + NNODES) - (char*)as1;
  // ---- end zero region ----
  float* alp1  = (float*)alloc((size_t)NETOT * 8 * 4);         // edge-major [NETOT][8]
  float* alp2  = (float*)alloc((size_t)NETOT * 4);
  int* offs    = (int*)alloc((size_t)(NNODES + 1) * 4);
  int* cursor  = (int*)alloc((size_t)NNODES * 4);
  int* csrsrc  = (int*)alloc((size_t)NETOT * 4);
  int* lscan   = (int*)alloc((size_t)NSCANB * 256 * 4);
  int* bsum    = (int*)alloc((size_t)NSCANB * 4);
  int* bbase   = (int*)alloc((size_t)NSCANB * 4);

  u16* W1bf = Wbf;
  u16* W2bf = Wbf + W1N;
  u16* oWbf = Wbf + W1N + W2N;

  hipMemsetAsync(as1, 0, zspan, stream);

  // CSR build
  count_edges<<<(NETOT + 255) / 256, 256, 0, stream>>>(edges, counts);
  scan_a<<<NSCANB, 256, 0, stream>>>(counts, lscan, bsum);
  scan_b<<<1, 128, 0, stream>>>(bsum, bbase);
  scan_c<<<NSCANB, 256, 0, stream>>>(lscan, counts, bbase, offs, cursor);
  fill_edges<<<(NETOT + 255) / 256, 256, 0, stream>>>(edges, cursor, csrsrc);

  // layer 0 embed + weight conversions, fused
  prep<<<(EMB0N + W1N + W2N + OWN + 255) / 256, 256, 0, stream>>>(
      cons, cols, node_W, node_b, col_W, col_b, W1, W2, out_W, emb0, Wbf);

  // GAT layer 1: GEMM (fused dots, head-major out) -> alpha (edge-major) -> SpMM
  gemm_bt<true, true, false, false><<<dim3((NNODES + 127) / 128, 1024 / 128), 256, 0, stream>>>(
      emb0, W1bf, nullptr, xp1h, att_s1, att_d1, as1, ad1, NNODES, 1024, 128);
  alpha1_k<<<(NNODES + 3) / 4, 256, 0, stream>>>(offs, csrsrc, as1, ad1, alp1);
  spmm1<<<8 * ((NNODES + 3) / 4), 256, 0, stream>>>(offs, csrsrc, alp1, xp1h, b1, emb2);

  // GAT layer 2: GEMM (fused dots) -> alpha -> SpMM
  gemm_bt<true, false, false, false><<<dim3((NNODES + 127) / 128, 1), 256, 0, stream>>>(
      emb2, W2bf, nullptr, xp2, att_s2, att_d2, as2, ad2, NNODES, 128, 1024);
  alpha2_k<<<(NNODES + 3) / 4, 256, 0, stream>>>(offs, csrsrc, as2, ad2, alp2);
  spmm2<<<(NNODES + 3) / 4, 256, 0, stream>>>(offs, csrsrc, alp2, xp2, b2, emb3);

  // output projection: rows 10000..19999, f32 out with bias
  gemm_bt<false, false, true, true><<<dim3((NCOLSN + 127) / 128, 1), 256, 0, stream>>>(
      emb3 + (size_t)NCONS * 128, oWbf, out_b, d_out, nullptr, nullptr, nullptr, nullptr,
      NCOLSN, 128, 128);
}